// Round 1
// baseline (943.030 us; speedup 1.0000x reference)
//
#include <hip/hip_runtime.h>
#include <hip/hip_bf16.h>

// Problem constants (structure baked in; N/E derived from in_sizes)
#define Dk 128
#define Hk 256
#define Ok 64
#define BN_EPS 1e-5f

#define BM 64
#define BNt 64
#define BK 16

// ---------------- degree / CSR build ----------------

__global__ void count_kernel(const int* __restrict__ col, int* __restrict__ cnt, int E) {
    int e = blockIdx.x * blockDim.x + threadIdx.x;
    if (e < E) atomicAdd(&cnt[col[e]], 1);
}

__global__ void dinv_kernel(const int* __restrict__ cnt, float* __restrict__ dinv, int n) {
    int i = blockIdx.x * blockDim.x + threadIdx.x;
    if (i < n) dinv[i] = rsqrtf((float)cnt[i] + 1.0f);  // +1 self loop
}

__global__ void scan_kernel(const int* __restrict__ cnt, int* __restrict__ off, int n) {
    __shared__ int sm[1024];
    __shared__ int carry_s;
    int t = threadIdx.x;
    if (t == 0) { carry_s = 0; off[0] = 0; }
    __syncthreads();
    for (int base = 0; base < n; base += 1024) {
        int i = base + t;
        int v = (i < n) ? cnt[i] : 0;
        sm[t] = v;
        __syncthreads();
        #pragma unroll
        for (int s = 1; s < 1024; s <<= 1) {
            int add = (t >= s) ? sm[t - s] : 0;
            __syncthreads();
            sm[t] += add;
            __syncthreads();
        }
        int carry = carry_s;
        if (i < n) off[i + 1] = carry + sm[t];
        __syncthreads();
        if (t == 0) carry_s = carry + sm[1023];
        __syncthreads();
    }
}

__global__ void fill_kernel(const int* __restrict__ row, const int* __restrict__ col,
                            const int* __restrict__ off, int* __restrict__ fillc,
                            int* __restrict__ csr, int E) {
    int e = blockIdx.x * blockDim.x + threadIdx.x;
    if (e < E) {
        int c = col[e];
        int p = atomicAdd(&fillc[c], 1);
        csr[off[c] + p] = row[e];
    }
}

// ---------------- f32 tiled GEMM: C[n,Hout] = A[n,K] @ W[K,Hout] ----------------
// gidx != nullptr => A row r is A[gidx[r]] (first-layer embedding gather)

__global__ __launch_bounds__(256) void gemm_f32(
    const float* __restrict__ A, const float* __restrict__ W, float* __restrict__ C,
    int n, int K, int Hout, const int* __restrict__ gidx)
{
    __shared__ float As[BK][BM];
    __shared__ float Bs[BK][BNt];
    const int tid = threadIdx.x;
    const int tx = tid & 15;
    const int ty = tid >> 4;
    const int bm = blockIdx.x * BM;
    const int bn = blockIdx.y * BNt;
    const int bcol = tid & 63;
    const int brow = tid >> 6;
    float acc[4][4] = {};

    for (int k0 = 0; k0 < K; k0 += BK) {
        #pragma unroll
        for (int rr = 0; rr < 4; ++rr) {
            int m = ty + rr * 16;
            int grow = bm + m;
            float v = 0.f;
            if (grow < n) {
                int ar = gidx ? gidx[grow] : grow;
                v = A[(size_t)ar * K + (k0 + tx)];
            }
            As[tx][m] = v;
        }
        #pragma unroll
        for (int rr = 0; rr < 4; ++rr) {
            int kk = brow + rr * 4;
            Bs[kk][bcol] = W[(size_t)(k0 + kk) * Hout + (bn + bcol)];
        }
        __syncthreads();
        #pragma unroll
        for (int k = 0; k < BK; ++k) {
            float a[4], b[4];
            #pragma unroll
            for (int i = 0; i < 4; ++i) a[i] = As[k][ty * 4 + i];
            #pragma unroll
            for (int j = 0; j < 4; ++j) b[j] = Bs[k][tx * 4 + j];
            #pragma unroll
            for (int i = 0; i < 4; ++i)
                #pragma unroll
                for (int j = 0; j < 4; ++j)
                    acc[i][j] = fmaf(a[i], b[j], acc[i][j]);
        }
        __syncthreads();
    }
    #pragma unroll
    for (int i = 0; i < 4; ++i) {
        int grow = bm + ty * 4 + i;
        if (grow < n) {
            float4 v = make_float4(acc[i][0], acc[i][1], acc[i][2], acc[i][3]);
            *(float4*)&C[(size_t)grow * Hout + bn + tx * 4] = v;
        }
    }
}

// ---------------- CSR-pull aggregation ----------------
// out[i] = dinv[i] * ( sum_{e in-edges} dinv[src]*xl[src] + dinv[i]*xl[i] ) + bias

__global__ __launch_bounds__(256) void aggregate_h(
    const float* __restrict__ xl, const int* __restrict__ csr,
    const int* __restrict__ off, const float* __restrict__ dinv,
    const float* __restrict__ bias, float* __restrict__ out, int n)
{
    int i = blockIdx.x;
    int f = threadIdx.x;
    float di = dinv[i];
    float acc = di * xl[(size_t)i * Hk + f];
    int e0 = off[i], e1 = off[i + 1];
    for (int e = e0; e < e1; ++e) {
        int r = csr[e];
        acc = fmaf(dinv[r], xl[(size_t)r * Hk + f], acc);
    }
    out[(size_t)i * Hk + f] = fmaf(di, acc, bias[f]);
}

__global__ __launch_bounds__(256) void aggregate_o(
    const float* __restrict__ xl, const int* __restrict__ csr,
    const int* __restrict__ off, const float* __restrict__ dinv,
    const float* __restrict__ bias, float* __restrict__ out, int n)
{
    int i = blockIdx.x * 4 + (threadIdx.x >> 6);
    int f = threadIdx.x & 63;
    if (i >= n) return;
    float di = dinv[i];
    float acc = di * xl[(size_t)i * Ok + f];
    int e0 = off[i], e1 = off[i + 1];
    for (int e = e0; e < e1; ++e) {
        int r = csr[e];
        acc = fmaf(dinv[r], xl[(size_t)r * Ok + f], acc);
    }
    out[(size_t)i * Ok + f] = fmaf(di, acc, bias[f]);
}

// ---------------- BatchNorm (training stats) ----------------

__global__ void bn_stats(const float* __restrict__ x, float* __restrict__ stats, int n) {
    int f = threadIdx.x;  // 256 columns
    float s = 0.f, sq = 0.f;
    for (int r = blockIdx.x; r < n; r += gridDim.x) {
        float v = x[(size_t)r * Hk + f];
        s += v; sq += v * v;
    }
    atomicAdd(&stats[f], s);
    atomicAdd(&stats[Hk + f], sq);
}

__global__ void bn_finalize(const float* __restrict__ stats, const float* __restrict__ g,
                            const float* __restrict__ be, float* __restrict__ ss, float invn) {
    int f = threadIdx.x;
    float mean = stats[f] * invn;
    float var = stats[Hk + f] * invn - mean * mean;
    float sc = g[f] * rsqrtf(var + BN_EPS);
    ss[f] = sc;
    ss[Hk + f] = fmaf(-mean, sc, be[f]);
}

__global__ void bn_apply_relu(float* __restrict__ x, const float* __restrict__ ss, size_t total) {
    size_t idx = ((size_t)blockIdx.x * blockDim.x + threadIdx.x) * 4;
    if (idx >= total) return;
    float4 v = *(const float4*)&x[idx];
    int f = (int)(idx & (Hk - 1));
    float4 sc = *(const float4*)&ss[f];
    float4 sh = *(const float4*)&ss[Hk + f];
    float4 r;
    r.x = fmaxf(fmaf(v.x, sc.x, sh.x), 0.f);
    r.y = fmaxf(fmaf(v.y, sc.y, sh.y), 0.f);
    r.z = fmaxf(fmaf(v.z, sc.z, sh.z), 0.f);
    r.w = fmaxf(fmaf(v.w, sc.w, sh.w), 0.f);
    *(float4*)&x[idx] = r;
}

// ---------------- host launch ----------------

extern "C" void kernel_launch(void* const* d_in, const int* in_sizes, int n_in,
                              void* d_out, int out_size, void* d_ws, size_t ws_size,
                              hipStream_t stream) {
    const int*   x_idx = (const int*)d_in[0];
    const int*   ei    = (const int*)d_in[1];
    const float* emb   = (const float*)d_in[2];
    const float* W1    = (const float*)d_in[3];
    const float* b1    = (const float*)d_in[4];
    const float* g1    = (const float*)d_in[5];
    const float* be1   = (const float*)d_in[6];
    const float* W2    = (const float*)d_in[7];
    const float* b2    = (const float*)d_in[8];
    const float* g2    = (const float*)d_in[9];
    const float* be2   = (const float*)d_in[10];
    const float* W3    = (const float*)d_in[11];
    const float* b3    = (const float*)d_in[12];

    const int N = in_sizes[0];
    const int E = in_sizes[1] / 2;
    const int* erow = ei;          // source
    const int* ecol = ei + E;      // target (aggregation index)

    // workspace layout (256B aligned bumps)
    char* p = (char*)d_ws;
    auto alloc = [&](size_t bytes) { char* q = p; p += (bytes + 255) & ~(size_t)255; return q; };
    float* dinv  = (float*)alloc((size_t)N * 4);
    int*   cnt   = (int*)  alloc((size_t)N * 4);
    int*   off   = (int*)  alloc((size_t)(N + 1) * 4);
    int*   fillc = (int*)  alloc((size_t)N * 4);
    int*   csr   = (int*)  alloc((size_t)E * 4);
    float* stats = (float*)alloc((size_t)2 * Hk * 4);
    float* ss    = (float*)alloc((size_t)2 * Hk * 4);
    float* bufA  = (float*)alloc((size_t)N * Hk * 4);
    float* bufB  = (float*)alloc((size_t)N * Hk * 4);

    // --- graph preprocessing ---
    hipMemsetAsync(cnt, 0, (size_t)N * 4, stream);
    hipMemsetAsync(fillc, 0, (size_t)N * 4, stream);
    count_kernel<<<(E + 255) / 256, 256, 0, stream>>>(ecol, cnt, E);
    dinv_kernel<<<(N + 255) / 256, 256, 0, stream>>>(cnt, dinv, N);
    scan_kernel<<<1, 1024, 0, stream>>>(cnt, off, N);
    fill_kernel<<<(E + 255) / 256, 256, 0, stream>>>(erow, ecol, off, fillc, csr, E);

    dim3 gemm_block(256);
    int rowBlocks = (N + BM - 1) / BM;
    size_t totalH = (size_t)N * Hk;
    int applyBlocks = (int)((totalH / 4 + 255) / 256);

    // --- layer 1: emb[x_idx] @ W1 -> agg -> BN -> ReLU ---
    gemm_f32<<<dim3(rowBlocks, Hk / BNt), gemm_block, 0, stream>>>(emb, W1, bufA, N, Dk, Hk, x_idx);
    aggregate_h<<<N, 256, 0, stream>>>(bufA, csr, off, dinv, b1, bufB, N);
    hipMemsetAsync(stats, 0, 2 * Hk * 4, stream);
    bn_stats<<<512, 256, 0, stream>>>(bufB, stats, N);
    bn_finalize<<<1, 256, 0, stream>>>(stats, g1, be1, ss, 1.0f / N);
    bn_apply_relu<<<applyBlocks, 256, 0, stream>>>(bufB, ss, totalH);

    // --- layer 2 ---
    gemm_f32<<<dim3(rowBlocks, Hk / BNt), gemm_block, 0, stream>>>(bufB, W2, bufA, N, Hk, Hk, nullptr);
    aggregate_h<<<N, 256, 0, stream>>>(bufA, csr, off, dinv, b2, bufB, N);
    hipMemsetAsync(stats, 0, 2 * Hk * 4, stream);
    bn_stats<<<512, 256, 0, stream>>>(bufB, stats, N);
    bn_finalize<<<1, 256, 0, stream>>>(stats, g2, be2, ss, 1.0f / N);
    bn_apply_relu<<<applyBlocks, 256, 0, stream>>>(bufB, ss, totalH);

    // --- layer 3: -> d_out ---
    gemm_f32<<<dim3(rowBlocks, Ok / BNt), gemm_block, 0, stream>>>(bufB, W3, bufA, N, Hk, Ok, nullptr);
    aggregate_o<<<(N + 3) / 4, 256, 0, stream>>>(bufA, csr, off, dinv, b3, (float*)d_out, N);
}

// Round 2
// 581.893 us; speedup vs baseline: 1.6206x; 1.6206x over previous
//
#include <hip/hip_runtime.h>
#include <hip/hip_bf16.h>

#define Dk 128
#define Hk 256
#define Ok 64
#define BN_EPS 1e-5f

typedef __attribute__((ext_vector_type(8))) short short8;
typedef __attribute__((ext_vector_type(4))) float f32x4;

static __device__ __forceinline__ float bf2f(ushort u) {
    union { uint32_t i; float f; } c; c.i = ((uint32_t)u) << 16; return c.f;
}
static __device__ __forceinline__ ushort f2bf(float f) {
    union { float f; uint32_t u; } c; c.f = f;
    return (ushort)((c.u + 0x7fffu + ((c.u >> 16) & 1u)) >> 16);
}

// ---------------- degree / CSR build ----------------

__global__ void count_kernel(const int* __restrict__ col, int* __restrict__ cnt, int E) {
    int e = blockIdx.x * blockDim.x + threadIdx.x;
    if (e < E) atomicAdd(&cnt[col[e]], 1);
}

__global__ void dinv_kernel(const int* __restrict__ cnt, float* __restrict__ dinv, int n) {
    int i = blockIdx.x * blockDim.x + threadIdx.x;
    if (i < n) dinv[i] = rsqrtf((float)cnt[i] + 1.0f);  // +1 self loop
}

__global__ void block_sum_kernel(const int* __restrict__ cnt, int* __restrict__ bsum, int n) {
    __shared__ int sm[256];
    int i = blockIdx.x * 256 + threadIdx.x;
    sm[threadIdx.x] = (i < n) ? cnt[i] : 0;
    __syncthreads();
    for (int s = 128; s; s >>= 1) {
        if (threadIdx.x < s) sm[threadIdx.x] += sm[threadIdx.x + s];
        __syncthreads();
    }
    if (!threadIdx.x) bsum[blockIdx.x] = sm[0];
}

__global__ void scan_base_kernel(int* __restrict__ bsum, int nb) {
    // single block: in-place exclusive scan of bsum
    __shared__ int sm[256];
    int t = threadIdx.x;
    int carry = 0;
    for (int base = 0; base < nb; base += 256) {
        int i = base + t;
        int v = (i < nb) ? bsum[i] : 0;
        sm[t] = v;
        __syncthreads();
        for (int s = 1; s < 256; s <<= 1) {
            int add = (t >= s) ? sm[t - s] : 0;
            __syncthreads();
            sm[t] += add;
            __syncthreads();
        }
        if (i < nb) bsum[i] = carry + sm[t] - v;  // exclusive
        int tot = sm[255];
        __syncthreads();
        carry += tot;
    }
}

__global__ void scan_final_kernel(const int* __restrict__ cnt, const int* __restrict__ bbase,
                                  int* __restrict__ offv, int n) {
    __shared__ int sm[256];
    int t = threadIdx.x, i = blockIdx.x * 256 + t;
    int v = (i < n) ? cnt[i] : 0;
    sm[t] = v;
    __syncthreads();
    for (int s = 1; s < 256; s <<= 1) {
        int add = (t >= s) ? sm[t - s] : 0;
        __syncthreads();
        sm[t] += add;
        __syncthreads();
    }
    if (i < n) offv[i + 1] = bbase[blockIdx.x] + sm[t];
    if (i == 0) offv[0] = 0;
}

__global__ void fill_kernel(const int* __restrict__ row, const int* __restrict__ col,
                            const int* __restrict__ off, int* __restrict__ fillc,
                            int* __restrict__ csr, int E) {
    int e = blockIdx.x * blockDim.x + threadIdx.x;
    if (e < E) {
        int c = col[e];
        int p = atomicAdd(&fillc[c], 1);
        csr[off[c] + p] = row[e];
    }
}

// ---------------- conversions ----------------

__global__ void emb_cvt_kernel(const float* __restrict__ emb, const int* __restrict__ xidx,
                               ushort* __restrict__ out, int n) {
    int gid = blockIdx.x * 256 + threadIdx.x;  // one thread per 8 elems
    int total = n * (Dk / 8);
    if (gid >= total) return;
    int node = gid >> 4, seg = gid & 15;       // Dk/8 = 16
    int src = xidx[node];
    const float* p = &emb[(size_t)src * Dk + seg * 8];
    float4 lo = *(const float4*)p, hi = *(const float4*)(p + 4);
    ushort r[8] = {f2bf(lo.x), f2bf(lo.y), f2bf(lo.z), f2bf(lo.w),
                   f2bf(hi.x), f2bf(hi.y), f2bf(hi.z), f2bf(hi.w)};
    *(short8*)&out[(size_t)gid * 8] = *(short8*)r;
}

__global__ void wcvt_kernel(const float* __restrict__ in, ushort* __restrict__ out, int sz) {
    int i = blockIdx.x * 256 + threadIdx.x;
    if (i < sz) out[i] = f2bf(in[i]);
}

// ---------------- bf16 MFMA GEMM: C[n,Hout] = A[n,KD] @ W[KD,Hout] ----------------
// BN_A: apply y = relu(sc[k]*x + sh[k]) to A during staging (ss = [sc|sh], 2*KD floats)
// STATS: accumulate per-column sum/sumsq of (C+bias) into stats[2*Hout] via atomics
// BIAS: add bias[col] in epilogue

template<int KD, bool BN_A, bool STATS, bool BIAS>
__global__ __launch_bounds__(256) void gemm_bf16(
    const ushort* __restrict__ A, const ushort* __restrict__ W,
    ushort* __restrict__ Cout, int n, int Hout,
    const float* __restrict__ bias, const float* __restrict__ ss,
    float* __restrict__ stats)
{
    __shared__ ushort As[64][40];   // 64 rows x 32 k (+8 pad)
    __shared__ ushort Bs[64][40];   // 64 cols x 32 k (+8 pad)
    const int tid = threadIdx.x;
    const int bm = blockIdx.x * 64;
    const int bn = blockIdx.y * 64;
    const int lane = tid & 63;
    const int wid = tid >> 6;
    const int wr = wid >> 1, wc = wid & 1;
    const int lr = lane & 15, lg = lane >> 4;

    f32x4 acc[2][2] = {};
    const int arow = tid >> 2, aseg = tid & 3;
    const int bcol = tid & 63, bkb = (tid >> 6) * 8;

    for (int k0 = 0; k0 < KD; k0 += 32) {
        // stage A (16B per thread)
        short8 av = {};
        if (bm + arow < n) {
            av = *(const short8*)&A[(size_t)(bm + arow) * KD + k0 + aseg * 8];
            if (BN_A) {
                #pragma unroll
                for (int j = 0; j < 8; ++j) {
                    int kf = k0 + aseg * 8 + j;
                    float v = bf2f((ushort)av[j]);
                    v = fmaxf(fmaf(v, ss[kf], ss[KD + kf]), 0.f);
                    av[j] = (short)f2bf(v);
                }
            }
        }
        *(short8*)&As[arow][aseg * 8] = av;
        // stage B transposed: Bs[col][k]
        #pragma unroll
        for (int j = 0; j < 8; ++j)
            Bs[bcol][bkb + j] = W[(size_t)(k0 + bkb + j) * Hout + bn + bcol];
        __syncthreads();
        // 4 MFMA per wave
        short8 af0 = *(const short8*)&As[wr * 32 + lr][lg * 8];
        short8 af1 = *(const short8*)&As[wr * 32 + 16 + lr][lg * 8];
        short8 bf0 = *(const short8*)&Bs[wc * 32 + lr][lg * 8];
        short8 bf1 = *(const short8*)&Bs[wc * 32 + 16 + lr][lg * 8];
        acc[0][0] = __builtin_amdgcn_mfma_f32_16x16x32_bf16(af0, bf0, acc[0][0], 0, 0, 0);
        acc[0][1] = __builtin_amdgcn_mfma_f32_16x16x32_bf16(af0, bf1, acc[0][1], 0, 0, 0);
        acc[1][0] = __builtin_amdgcn_mfma_f32_16x16x32_bf16(af1, bf0, acc[1][0], 0, 0, 0);
        acc[1][1] = __builtin_amdgcn_mfma_f32_16x16x32_bf16(af1, bf1, acc[1][1], 0, 0, 0);
        __syncthreads();
    }

    // epilogue: bias add, bf16 store, optional column stats
    float s[2] = {0.f, 0.f}, q[2] = {0.f, 0.f};
    #pragma unroll
    for (int nn = 0; nn < 2; ++nn) {
        int col = bn + wc * 32 + nn * 16 + lr;
        float bv = BIAS ? bias[col] : 0.f;
        #pragma unroll
        for (int m = 0; m < 2; ++m) {
            #pragma unroll
            for (int i = 0; i < 4; ++i) {
                int grow = bm + wr * 32 + m * 16 + lg * 4 + i;
                if (grow < n) {
                    float v = acc[m][nn][i] + bv;
                    Cout[(size_t)grow * Hout + col] = f2bf(v);
                    if (STATS) { s[nn] += v; q[nn] += v * v; }
                }
            }
        }
    }
    if (STATS) {
        #pragma unroll
        for (int nn = 0; nn < 2; ++nn) {
            s[nn] += __shfl_xor(s[nn], 16);
            q[nn] += __shfl_xor(q[nn], 16);
            s[nn] += __shfl_xor(s[nn], 32);
            q[nn] += __shfl_xor(q[nn], 32);
            if (lg == 0) {
                int col = bn + wc * 32 + nn * 16 + lr;
                atomicAdd(&stats[col], s[nn]);
                atomicAdd(&stats[Hout + col], q[nn]);
            }
        }
    }
}

__global__ void bn_finalize_kernel(const float* __restrict__ stats, const float* __restrict__ g,
                                   const float* __restrict__ be, float* __restrict__ ss,
                                   float invn, int Hf) {
    int f = threadIdx.x;
    float mean = stats[f] * invn;
    float var = stats[Hf + f] * invn - mean * mean;
    float sc = g[f] * rsqrtf(var + BN_EPS);
    ss[f] = sc;
    ss[Hf + f] = fmaf(-mean, sc, be[f]);
}

// ---------------- CSR-pull aggregation (bf16 in) ----------------
// MODE 0: plain -> bf16 out
// MODE 1: apply relu(sc*x+sh) to each gathered element -> bf16 out
// MODE 2: + bias -> f32 out
// out[i] = di * ( sum_nbr dinv[r]*f(x[r]) + di*f(x[i]) )  [+ bias]

template<int FH, int MODE>
__global__ __launch_bounds__(256) void agg_kernel(
    const ushort* __restrict__ x, const int* __restrict__ csr, const int* __restrict__ off,
    const float* __restrict__ dinv, const float* __restrict__ ss,
    const float* __restrict__ bias, void* __restrict__ outp, int n)
{
    constexpr int TPN = FH / 2;       // threads per node (2 feats each)
    constexpr int NPB = 256 / TPN;    // nodes per block
    int node = blockIdx.x * NPB + threadIdx.x / TPN;
    int f2 = (threadIdx.x % TPN) * 2;
    if (node >= n) return;
    float sc0 = 0.f, sh0 = 0.f, sc1 = 0.f, sh1 = 0.f;
    if (MODE == 1) { sc0 = ss[f2]; sc1 = ss[f2 + 1]; sh0 = ss[FH + f2]; sh1 = ss[FH + f2 + 1]; }
    float di = dinv[node];
    ushort2 u = *(const ushort2*)&x[(size_t)node * FH + f2];
    float a = bf2f(u.x), b = bf2f(u.y);
    if (MODE == 1) { a = fmaxf(fmaf(a, sc0, sh0), 0.f); b = fmaxf(fmaf(b, sc1, sh1), 0.f); }
    float acc0 = di * a, acc1 = di * b;
    int e1 = off[node + 1];
    for (int e = off[node]; e < e1; ++e) {
        int r = csr[e];
        float dr = dinv[r];
        ushort2 w = *(const ushort2*)&x[(size_t)r * FH + f2];
        float c0 = bf2f(w.x), c1 = bf2f(w.y);
        if (MODE == 1) { c0 = fmaxf(fmaf(c0, sc0, sh0), 0.f); c1 = fmaxf(fmaf(c1, sc1, sh1), 0.f); }
        acc0 = fmaf(dr, c0, acc0);
        acc1 = fmaf(dr, c1, acc1);
    }
    acc0 *= di; acc1 *= di;
    if (MODE == 2) {
        float* o = (float*)outp;
        o[(size_t)node * FH + f2]     = acc0 + bias[f2];
        o[(size_t)node * FH + f2 + 1] = acc1 + bias[f2 + 1];
    } else {
        ushort2 o; o.x = f2bf(acc0); o.y = f2bf(acc1);
        *(ushort2*)((ushort*)outp + (size_t)node * FH + f2) = o;
    }
}

// ---------------- host launch ----------------

extern "C" void kernel_launch(void* const* d_in, const int* in_sizes, int n_in,
                              void* d_out, int out_size, void* d_ws, size_t ws_size,
                              hipStream_t stream) {
    const int*   x_idx = (const int*)d_in[0];
    const int*   ei    = (const int*)d_in[1];
    const float* emb   = (const float*)d_in[2];
    const float* W1    = (const float*)d_in[3];
    const float* b1    = (const float*)d_in[4];
    const float* g1    = (const float*)d_in[5];
    const float* be1   = (const float*)d_in[6];
    const float* W2    = (const float*)d_in[7];
    const float* b2    = (const float*)d_in[8];
    const float* g2    = (const float*)d_in[9];
    const float* be2   = (const float*)d_in[10];
    const float* W3    = (const float*)d_in[11];
    const float* b3    = (const float*)d_in[12];

    const int N = in_sizes[0];
    const int E = in_sizes[1] / 2;
    const int* erow = ei;       // source
    const int* ecol = ei + E;   // target

    char* p = (char*)d_ws;
    auto alloc = [&](size_t bytes) { char* q = p; p += (bytes + 255) & ~(size_t)255; return q; };
    const int nb = (N + 255) / 256;
    float*  dinv  = (float*) alloc((size_t)N * 4);
    int*    cnt   = (int*)   alloc((size_t)N * 4);
    int*    off   = (int*)   alloc((size_t)(N + 1) * 4);
    int*    fillc = (int*)   alloc((size_t)N * 4);
    int*    bsum  = (int*)   alloc((size_t)nb * 4);
    int*    csr   = (int*)   alloc((size_t)E * 4);
    float*  stats1= (float*) alloc(2 * Hk * 4);
    float*  ss1   = (float*) alloc(2 * Hk * 4);
    float*  stats2= (float*) alloc(2 * Hk * 4);
    float*  ss2   = (float*) alloc(2 * Hk * 4);
    ushort* W1b   = (ushort*)alloc((size_t)Dk * Hk * 2);
    ushort* W2b   = (ushort*)alloc((size_t)Hk * Hk * 2);
    ushort* W3b   = (ushort*)alloc((size_t)Hk * Ok * 2);
    ushort* embb  = (ushort*)alloc((size_t)N * Dk * 2);
    ushort* agg1b = (ushort*)alloc((size_t)N * Dk * 2);
    ushort* conv1b= (ushort*)alloc((size_t)N * Hk * 2);  // reused as conv2 out
    ushort* agg2b = (ushort*)alloc((size_t)N * Hk * 2);
    ushort* xl3b  = (ushort*)alloc((size_t)N * Ok * 2);

    // --- graph preprocessing ---
    hipMemsetAsync(cnt, 0, (size_t)N * 4, stream);
    hipMemsetAsync(fillc, 0, (size_t)N * 4, stream);
    hipMemsetAsync(stats1, 0, 2 * Hk * 4, stream);
    hipMemsetAsync(stats2, 0, 2 * Hk * 4, stream);
    count_kernel<<<(E + 255) / 256, 256, 0, stream>>>(ecol, cnt, E);
    dinv_kernel<<<nb, 256, 0, stream>>>(cnt, dinv, N);
    block_sum_kernel<<<nb, 256, 0, stream>>>(cnt, bsum, N);
    scan_base_kernel<<<1, 256, 0, stream>>>(bsum, nb);
    scan_final_kernel<<<nb, 256, 0, stream>>>(cnt, bsum, off, N);
    fill_kernel<<<(E + 255) / 256, 256, 0, stream>>>(erow, ecol, off, fillc, csr, E);

    // --- input conversions ---
    emb_cvt_kernel<<<(N * (Dk / 8) + 255) / 256, 256, 0, stream>>>(emb, x_idx, embb, N);
    wcvt_kernel<<<(Dk * Hk + 255) / 256, 256, 0, stream>>>(W1, W1b, Dk * Hk);
    wcvt_kernel<<<(Hk * Hk + 255) / 256, 256, 0, stream>>>(W2, W2b, Hk * Hk);
    wcvt_kernel<<<(Hk * Ok + 255) / 256, 256, 0, stream>>>(W3, W3b, Hk * Ok);

    const int rowBlocks = (N + 63) / 64;

    // --- layer 1: agg(emb) @ W1 + b1 -> conv1 (stats fused) ---
    agg_kernel<Dk, 0><<<(N + 3) / 4, 256, 0, stream>>>(embb, csr, off, dinv, nullptr, nullptr, agg1b, N);
    gemm_bf16<Dk, false, true, true><<<dim3(rowBlocks, Hk / 64), 256, 0, stream>>>(
        agg1b, W1b, conv1b, N, Hk, b1, nullptr, stats1);
    bn_finalize_kernel<<<1, Hk, 0, stream>>>(stats1, g1, be1, ss1, 1.0f / N, Hk);

    // --- layer 2: agg(relu(bn(conv1))) @ W2 + b2 -> conv2 (stats fused) ---
    agg_kernel<Hk, 1><<<(N + 1) / 2, 256, 0, stream>>>(conv1b, csr, off, dinv, ss1, nullptr, agg2b, N);
    gemm_bf16<Hk, false, true, true><<<dim3(rowBlocks, Hk / 64), 256, 0, stream>>>(
        agg2b, W2b, conv1b /* conv2 */, N, Hk, b2, nullptr, stats2);
    bn_finalize_kernel<<<1, Hk, 0, stream>>>(stats2, g2, be2, ss2, 1.0f / N, Hk);

    // --- layer 3: (relu(bn(conv2)) @ W3) aggregated + b3 -> d_out ---
    gemm_bf16<Hk, true, false, false><<<dim3(rowBlocks, Ok / 64), 256, 0, stream>>>(
        conv1b, W3b, xl3b, N, Ok, nullptr, ss2, nullptr);
    agg_kernel<Ok, 2><<<(N + 7) / 8, 256, 0, stream>>>(xl3b, csr, off, dinv, nullptr, b3, d_out, N);
}

// Round 3
// 443.501 us; speedup vs baseline: 2.1263x; 1.3120x over previous
//
#include <hip/hip_runtime.h>
#include <hip/hip_bf16.h>

#define Dk 128
#define Hk 256
#define Ok 64
#define BN_EPS 1e-5f

typedef __attribute__((ext_vector_type(8))) short short8;
typedef __attribute__((ext_vector_type(4))) float f32x4;

static __device__ __forceinline__ float bf2f(ushort u) {
    union { uint32_t i; float f; } c; c.i = ((uint32_t)u) << 16; return c.f;
}
static __device__ __forceinline__ ushort f2bf(float f) {
    union { float f; uint32_t u; } c; c.f = f;
    return (ushort)((c.u + 0x7fffu + ((c.u >> 16) & 1u)) >> 16);
}

template<int V> __device__ __forceinline__ void loadv(ushort* d, const ushort* s);
template<> __device__ __forceinline__ void loadv<1>(ushort* d, const ushort* s) { d[0] = *s; }
template<> __device__ __forceinline__ void loadv<2>(ushort* d, const ushort* s) { *(ushort2*)d = *(const ushort2*)s; }
template<> __device__ __forceinline__ void loadv<4>(ushort* d, const ushort* s) { *(ushort4*)d = *(const ushort4*)s; }
template<int V> __device__ __forceinline__ void storev(ushort* d, const ushort* s);
template<> __device__ __forceinline__ void storev<1>(ushort* d, const ushort* s) { *d = s[0]; }
template<> __device__ __forceinline__ void storev<2>(ushort* d, const ushort* s) { *(ushort2*)d = *(const ushort2*)s; }
template<> __device__ __forceinline__ void storev<4>(ushort* d, const ushort* s) { *(ushort4*)d = *(const ushort4*)s; }

// ---------------- degree / CSR build ----------------

__global__ void count_kernel(const int* __restrict__ col, int* __restrict__ cnt, int E) {
    int e = blockIdx.x * blockDim.x + threadIdx.x;
    if (e < E) atomicAdd(&cnt[col[e]], 1);
}

__global__ void dinv_kernel(const int* __restrict__ cnt, float* __restrict__ dinv, int n) {
    int i = blockIdx.x * blockDim.x + threadIdx.x;
    if (i < n) dinv[i] = rsqrtf((float)cnt[i] + 1.0f);  // +1 self loop
}

__global__ void block_sum_kernel(const int* __restrict__ cnt, int* __restrict__ bsum, int n) {
    __shared__ int sm[256];
    int i = blockIdx.x * 256 + threadIdx.x;
    sm[threadIdx.x] = (i < n) ? cnt[i] : 0;
    __syncthreads();
    for (int s = 128; s; s >>= 1) {
        if (threadIdx.x < s) sm[threadIdx.x] += sm[threadIdx.x + s];
        __syncthreads();
    }
    if (!threadIdx.x) bsum[blockIdx.x] = sm[0];
}

__global__ void scan_base_kernel(int* __restrict__ bsum, int nb) {
    __shared__ int sm[256];
    int t = threadIdx.x;
    int carry = 0;
    for (int base = 0; base < nb; base += 256) {
        int i = base + t;
        int v = (i < nb) ? bsum[i] : 0;
        sm[t] = v;
        __syncthreads();
        for (int s = 1; s < 256; s <<= 1) {
            int add = (t >= s) ? sm[t - s] : 0;
            __syncthreads();
            sm[t] += add;
            __syncthreads();
        }
        if (i < nb) bsum[i] = carry + sm[t] - v;  // exclusive
        int tot = sm[255];
        __syncthreads();
        carry += tot;
    }
}

__global__ void scan_final_kernel(const int* __restrict__ cnt, const int* __restrict__ bbase,
                                  int* __restrict__ offv, int n) {
    __shared__ int sm[256];
    int t = threadIdx.x, i = blockIdx.x * 256 + t;
    int v = (i < n) ? cnt[i] : 0;
    sm[t] = v;
    __syncthreads();
    for (int s = 1; s < 256; s <<= 1) {
        int add = (t >= s) ? sm[t - s] : 0;
        __syncthreads();
        sm[t] += add;
        __syncthreads();
    }
    if (i < n) offv[i + 1] = bbase[blockIdx.x] + sm[t];
    if (i == 0) offv[0] = 0;
}

// packs (src_index, dinv[src]) per edge -> one uniform 8B load in agg
__global__ void fill_kernel(const int* __restrict__ row, const int* __restrict__ col,
                            const int* __restrict__ off, int* __restrict__ fillc,
                            const float* __restrict__ dinv, int2* __restrict__ ep, int E) {
    int e = blockIdx.x * blockDim.x + threadIdx.x;
    if (e < E) {
        int c = col[e], r = row[e];
        int p = atomicAdd(&fillc[c], 1);
        ep[off[c] + p] = make_int2(r, __float_as_int(dinv[r]));
    }
}

// ---------------- conversions ----------------

__global__ void emb_cvt_kernel(const float* __restrict__ emb, const int* __restrict__ xidx,
                               ushort* __restrict__ out, int n) {
    int gid = blockIdx.x * 256 + threadIdx.x;  // one thread per 8 elems
    int total = n * (Dk / 8);
    if (gid >= total) return;
    int node = gid >> 4, seg = gid & 15;       // Dk/8 = 16
    int src = xidx[node];
    const float* p = &emb[(size_t)src * Dk + seg * 8];
    float4 lo = *(const float4*)p, hi = *(const float4*)(p + 4);
    ushort r[8] = {f2bf(lo.x), f2bf(lo.y), f2bf(lo.z), f2bf(lo.w),
                   f2bf(hi.x), f2bf(hi.y), f2bf(hi.z), f2bf(hi.w)};
    *(short8*)&out[(size_t)gid * 8] = *(short8*)r;
}

__global__ void wcvt_kernel(const float* __restrict__ in, ushort* __restrict__ out, int sz) {
    int i = blockIdx.x * 256 + threadIdx.x;
    if (i < sz) out[i] = f2bf(in[i]);
}

// ---------------- bf16 MFMA GEMM: C[n,Hout] = A[n,KD] @ W[KD,Hout] ----------------

template<int KD, bool STATS, bool BIAS>
__global__ __launch_bounds__(256) void gemm_bf16(
    const ushort* __restrict__ A, const ushort* __restrict__ W,
    ushort* __restrict__ Cout, int n, int Hout,
    const float* __restrict__ bias, float* __restrict__ stats)
{
    __shared__ ushort As[64][40];
    __shared__ ushort Bs[64][40];
    const int tid = threadIdx.x;
    const int bm = blockIdx.x * 64;
    const int bn = blockIdx.y * 64;
    const int lane = tid & 63;
    const int wid = tid >> 6;
    const int wr = wid >> 1, wc = wid & 1;
    const int lr = lane & 15, lg = lane >> 4;

    f32x4 acc[2][2] = {};
    const int arow = tid >> 2, aseg = tid & 3;
    const int bcol = tid & 63, bkb = (tid >> 6) * 8;

    for (int k0 = 0; k0 < KD; k0 += 32) {
        short8 av = {};
        if (bm + arow < n)
            av = *(const short8*)&A[(size_t)(bm + arow) * KD + k0 + aseg * 8];
        *(short8*)&As[arow][aseg * 8] = av;
        #pragma unroll
        for (int j = 0; j < 8; ++j)
            Bs[bcol][bkb + j] = W[(size_t)(k0 + bkb + j) * Hout + bn + bcol];
        __syncthreads();
        short8 af0 = *(const short8*)&As[wr * 32 + lr][lg * 8];
        short8 af1 = *(const short8*)&As[wr * 32 + 16 + lr][lg * 8];
        short8 bf0 = *(const short8*)&Bs[wc * 32 + lr][lg * 8];
        short8 bf1 = *(const short8*)&Bs[wc * 32 + 16 + lr][lg * 8];
        acc[0][0] = __builtin_amdgcn_mfma_f32_16x16x32_bf16(af0, bf0, acc[0][0], 0, 0, 0);
        acc[0][1] = __builtin_amdgcn_mfma_f32_16x16x32_bf16(af0, bf1, acc[0][1], 0, 0, 0);
        acc[1][0] = __builtin_amdgcn_mfma_f32_16x16x32_bf16(af1, bf0, acc[1][0], 0, 0, 0);
        acc[1][1] = __builtin_amdgcn_mfma_f32_16x16x32_bf16(af1, bf1, acc[1][1], 0, 0, 0);
        __syncthreads();
    }

    float s[2] = {0.f, 0.f}, q[2] = {0.f, 0.f};
    #pragma unroll
    for (int nn = 0; nn < 2; ++nn) {
        int col = bn + wc * 32 + nn * 16 + lr;
        float bv = BIAS ? bias[col] : 0.f;
        #pragma unroll
        for (int m = 0; m < 2; ++m) {
            #pragma unroll
            for (int i = 0; i < 4; ++i) {
                int grow = bm + wr * 32 + m * 16 + lg * 4 + i;
                if (grow < n) {
                    float v = acc[m][nn][i] + bv;
                    Cout[(size_t)grow * Hout + col] = f2bf(v);
                    if (STATS) { s[nn] += v; q[nn] += v * v; }
                }
            }
        }
    }
    if (STATS) {
        #pragma unroll
        for (int nn = 0; nn < 2; ++nn) {
            s[nn] += __shfl_xor(s[nn], 16);
            q[nn] += __shfl_xor(q[nn], 16);
            s[nn] += __shfl_xor(s[nn], 32);
            q[nn] += __shfl_xor(q[nn], 32);
            if (lg == 0) {
                int col = bn + wc * 32 + nn * 16 + lr;
                atomicAdd(&stats[col], s[nn]);
                atomicAdd(&stats[Hout + col], q[nn]);
            }
        }
    }
}

__global__ void bn_finalize_kernel(const float* __restrict__ stats, const float* __restrict__ g,
                                   const float* __restrict__ be, float* __restrict__ ss,
                                   float invn, int Hf) {
    int f = threadIdx.x;
    float mean = stats[f] * invn;
    float var = stats[Hf + f] * invn - mean * mean;
    float sc = g[f] * rsqrtf(var + BN_EPS);
    ss[f] = sc;
    ss[Hf + f] = fmaf(-mean, sc, be[f]);
}

// y = relu(sc*x + sh), bf16 -> bf16, 8 elems/thread (Hk-wide rows)
__global__ __launch_bounds__(256) void bn_apply_kernel(
    const ushort* __restrict__ in, ushort* __restrict__ out,
    const float* __restrict__ ss, int total8)
{
    int gid = blockIdx.x * 256 + threadIdx.x;
    if (gid >= total8) return;
    size_t idx = (size_t)gid * 8;
    int f = (int)(idx & (Hk - 1));
    short8 a = *(const short8*)&in[idx];
    ushort r[8];
    #pragma unroll
    for (int j = 0; j < 8; ++j) {
        float v = bf2f((ushort)a[j]);
        r[j] = f2bf(fmaxf(fmaf(v, ss[f + j], ss[Hk + f + j]), 0.f));
    }
    *(short8*)&out[idx] = *(short8*)r;
}

// ---------------- CSR-pull aggregation: 1 wave/node, MLP-unrolled x4 ----------------
// out[i] = di * ( sum_nbr w_r * x[r] + di * x[i] )  [+ bias, f32 out]

template<int FH, bool OUT_F32>
__global__ __launch_bounds__(256) void agg_kernel(
    const ushort* __restrict__ x, const int2* __restrict__ ep, const int* __restrict__ off,
    const float* __restrict__ dinv, const float* __restrict__ bias,
    void* __restrict__ outp, int n)
{
    constexpr int VEC = FH / 64;
    const int lane = threadIdx.x & 63;
    const int node = blockIdx.x * 4 + (threadIdx.x >> 6);
    if (node >= n) return;
    const int fb = lane * VEC;
    const ushort* __restrict__ xb = x + fb;

    float di = dinv[node];
    float acc[VEC];
    {
        ushort t[VEC];
        loadv<VEC>(t, &xb[(size_t)node * FH]);
        #pragma unroll
        for (int v = 0; v < VEC; ++v) acc[v] = di * bf2f(t[v]);
    }
    const int e1 = off[node + 1];
    int e = off[node];
    for (; e + 4 <= e1; e += 4) {
        int2 p0 = ep[e], p1 = ep[e + 1], p2 = ep[e + 2], p3 = ep[e + 3];
        ushort t0[VEC], t1[VEC], t2[VEC], t3[VEC];
        loadv<VEC>(t0, &xb[(size_t)p0.x * FH]);
        loadv<VEC>(t1, &xb[(size_t)p1.x * FH]);
        loadv<VEC>(t2, &xb[(size_t)p2.x * FH]);
        loadv<VEC>(t3, &xb[(size_t)p3.x * FH]);
        float w0 = __int_as_float(p0.y), w1 = __int_as_float(p1.y);
        float w2 = __int_as_float(p2.y), w3 = __int_as_float(p3.y);
        #pragma unroll
        for (int v = 0; v < VEC; ++v) {
            acc[v] = fmaf(w0, bf2f(t0[v]), acc[v]);
            acc[v] = fmaf(w1, bf2f(t1[v]), acc[v]);
            acc[v] = fmaf(w2, bf2f(t2[v]), acc[v]);
            acc[v] = fmaf(w3, bf2f(t3[v]), acc[v]);
        }
    }
    for (; e < e1; ++e) {
        int2 pp = ep[e];
        ushort tt[VEC];
        loadv<VEC>(tt, &xb[(size_t)pp.x * FH]);
        float w = __int_as_float(pp.y);
        #pragma unroll
        for (int v = 0; v < VEC; ++v) acc[v] = fmaf(w, bf2f(tt[v]), acc[v]);
    }
    if (OUT_F32) {
        float* o = (float*)outp + (size_t)node * FH + fb;
        #pragma unroll
        for (int v = 0; v < VEC; ++v) o[v] = fmaf(di, acc[v], bias[fb + v]);
    } else {
        ushort ov[VEC];
        #pragma unroll
        for (int v = 0; v < VEC; ++v) ov[v] = f2bf(di * acc[v]);
        storev<VEC>((ushort*)outp + (size_t)node * FH + fb, ov);
    }
}

// ---------------- host launch ----------------

extern "C" void kernel_launch(void* const* d_in, const int* in_sizes, int n_in,
                              void* d_out, int out_size, void* d_ws, size_t ws_size,
                              hipStream_t stream) {
    const int*   x_idx = (const int*)d_in[0];
    const int*   ei    = (const int*)d_in[1];
    const float* emb   = (const float*)d_in[2];
    const float* W1    = (const float*)d_in[3];
    const float* b1    = (const float*)d_in[4];
    const float* g1    = (const float*)d_in[5];
    const float* be1   = (const float*)d_in[6];
    const float* W2    = (const float*)d_in[7];
    const float* b2    = (const float*)d_in[8];
    const float* g2    = (const float*)d_in[9];
    const float* be2   = (const float*)d_in[10];
    const float* W3    = (const float*)d_in[11];
    const float* b3    = (const float*)d_in[12];

    const int N = in_sizes[0];
    const int E = in_sizes[1] / 2;
    const int* erow = ei;       // source
    const int* ecol = ei + E;   // target

    char* p = (char*)d_ws;
    auto alloc = [&](size_t bytes) { char* q = p; p += (bytes + 255) & ~(size_t)255; return q; };
    const int nb = (N + 255) / 256;
    float*  dinv  = (float*) alloc((size_t)N * 4);
    int*    cnt   = (int*)   alloc((size_t)N * 4);
    int*    off   = (int*)   alloc((size_t)(N + 1) * 4);
    int*    fillc = (int*)   alloc((size_t)N * 4);
    int*    bsum  = (int*)   alloc((size_t)nb * 4);
    int2*   ep    = (int2*)  alloc((size_t)E * 8);
    float*  stats1= (float*) alloc(2 * Hk * 4);
    float*  ss1   = (float*) alloc(2 * Hk * 4);
    float*  stats2= (float*) alloc(2 * Hk * 4);
    float*  ss2   = (float*) alloc(2 * Hk * 4);
    ushort* W1b   = (ushort*)alloc((size_t)Dk * Hk * 2);
    ushort* W2b   = (ushort*)alloc((size_t)Hk * Hk * 2);
    ushort* W3b   = (ushort*)alloc((size_t)Hk * Ok * 2);
    // bufU: phase 1 holds embb (N*Dk) + agg1b (N*Dk); later reused as relu1b (N*Hk)
    ushort* bufU  = (ushort*)alloc((size_t)N * Hk * 2);
    ushort* embb  = bufU;
    ushort* agg1b = bufU + (size_t)N * Dk;
    ushort* relu1b= bufU;
    ushort* conv1b= (ushort*)alloc((size_t)N * Hk * 2);  // conv1, then conv2
    ushort* agg2b = (ushort*)alloc((size_t)N * Hk * 2);  // agg2, then relu2
    ushort* xl3b  = (ushort*)alloc((size_t)N * Ok * 2);

    // --- graph preprocessing ---
    hipMemsetAsync(cnt, 0, (size_t)N * 4, stream);
    hipMemsetAsync(fillc, 0, (size_t)N * 4, stream);
    hipMemsetAsync(stats1, 0, 2 * Hk * 4, stream);
    hipMemsetAsync(stats2, 0, 2 * Hk * 4, stream);
    count_kernel<<<(E + 255) / 256, 256, 0, stream>>>(ecol, cnt, E);
    dinv_kernel<<<nb, 256, 0, stream>>>(cnt, dinv, N);
    block_sum_kernel<<<nb, 256, 0, stream>>>(cnt, bsum, N);
    scan_base_kernel<<<1, 256, 0, stream>>>(bsum, nb);
    scan_final_kernel<<<nb, 256, 0, stream>>>(cnt, bsum, off, N);
    fill_kernel<<<(E + 255) / 256, 256, 0, stream>>>(erow, ecol, off, fillc, dinv, ep, E);

    // --- input conversions ---
    emb_cvt_kernel<<<(N * (Dk / 8) + 255) / 256, 256, 0, stream>>>(emb, x_idx, embb, N);
    wcvt_kernel<<<(Dk * Hk + 255) / 256, 256, 0, stream>>>(W1, W1b, Dk * Hk);
    wcvt_kernel<<<(Hk * Hk + 255) / 256, 256, 0, stream>>>(W2, W2b, Hk * Hk);
    wcvt_kernel<<<(Hk * Ok + 255) / 256, 256, 0, stream>>>(W3, W3b, Hk * Ok);

    const int rowBlocks = (N + 63) / 64;
    const int aggBlocks = (N + 3) / 4;
    const int applyBlocks = (N * (Hk / 8) + 255) / 256;

    // --- layer 1 ---
    agg_kernel<Dk, false><<<aggBlocks, 256, 0, stream>>>(embb, ep, off, dinv, nullptr, agg1b, N);
    gemm_bf16<Dk, true, true><<<dim3(rowBlocks, Hk / 64), 256, 0, stream>>>(
        agg1b, W1b, conv1b, N, Hk, b1, stats1);
    bn_finalize_kernel<<<1, Hk, 0, stream>>>(stats1, g1, be1, ss1, 1.0f / N, Hk);
    bn_apply_kernel<<<applyBlocks, 256, 0, stream>>>(conv1b, relu1b, ss1, N * (Hk / 8));

    // --- layer 2 ---
    agg_kernel<Hk, false><<<aggBlocks, 256, 0, stream>>>(relu1b, ep, off, dinv, nullptr, agg2b, N);
    gemm_bf16<Hk, true, true><<<dim3(rowBlocks, Hk / 64), 256, 0, stream>>>(
        agg2b, W2b, conv1b /* conv2 */, N, Hk, b2, stats2);
    bn_finalize_kernel<<<1, Hk, 0, stream>>>(stats2, g2, be2, ss2, 1.0f / N, Hk);
    bn_apply_kernel<<<applyBlocks, 256, 0, stream>>>(conv1b, agg2b /* relu2 */, ss2, N * (Hk / 8));

    // --- layer 3 ---
    gemm_bf16<Hk, false, false><<<dim3(rowBlocks, Ok / 64), 256, 0, stream>>>(
        agg2b, W3b, xl3b, N, Ok, nullptr, nullptr);
    agg_kernel<Ok, true><<<aggBlocks, 256, 0, stream>>>(xl3b, ep, off, dinv, b3, d_out, N);
}

// Round 4
// 362.159 us; speedup vs baseline: 2.6039x; 1.2246x over previous
//
#include <hip/hip_runtime.h>
#include <hip/hip_bf16.h>

#define Dk 128
#define Hk 256
#define Ok 64
#define BN_EPS 1e-5f

typedef __attribute__((ext_vector_type(8))) short short8;
typedef __attribute__((ext_vector_type(4))) float f32x4;

static __device__ __forceinline__ float bf2f(ushort u) {
    union { uint32_t i; float f; } c; c.i = ((uint32_t)u) << 16; return c.f;
}
static __device__ __forceinline__ ushort f2bf(float f) {
    union { float f; uint32_t u; } c; c.f = f;
    return (ushort)((c.u + 0x7fffu + ((c.u >> 16) & 1u)) >> 16);
}

template<int V> __device__ __forceinline__ void loadv(ushort* d, const ushort* s);
template<> __device__ __forceinline__ void loadv<1>(ushort* d, const ushort* s) { d[0] = *s; }
template<> __device__ __forceinline__ void loadv<2>(ushort* d, const ushort* s) { *(ushort2*)d = *(const ushort2*)s; }
template<> __device__ __forceinline__ void loadv<4>(ushort* d, const ushort* s) { *(ushort4*)d = *(const ushort4*)s; }
template<int V> __device__ __forceinline__ void storev(ushort* d, const ushort* s);
template<> __device__ __forceinline__ void storev<1>(ushort* d, const ushort* s) { *d = s[0]; }
template<> __device__ __forceinline__ void storev<2>(ushort* d, const ushort* s) { *(ushort2*)d = *(const ushort2*)s; }
template<> __device__ __forceinline__ void storev<4>(ushort* d, const ushort* s) { *(ushort4*)d = *(const ushort4*)s; }

// ---------------- degree / CSR build ----------------

__global__ void count_kernel(const int* __restrict__ col, int* __restrict__ cnt, int E) {
    int e = blockIdx.x * blockDim.x + threadIdx.x;
    if (e < E) atomicAdd(&cnt[col[e]], 1);
}

__global__ void dinv_kernel(const int* __restrict__ cnt, float* __restrict__ dinv, int n) {
    int i = blockIdx.x * blockDim.x + threadIdx.x;
    if (i < n) dinv[i] = rsqrtf((float)cnt[i] + 1.0f);  // +1 self loop
}

__global__ void block_sum_kernel(const int* __restrict__ cnt, int* __restrict__ bsum, int n) {
    __shared__ int sm[256];
    int i = blockIdx.x * 256 + threadIdx.x;
    sm[threadIdx.x] = (i < n) ? cnt[i] : 0;
    __syncthreads();
    for (int s = 128; s; s >>= 1) {
        if (threadIdx.x < s) sm[threadIdx.x] += sm[threadIdx.x + s];
        __syncthreads();
    }
    if (!threadIdx.x) bsum[blockIdx.x] = sm[0];
}

__global__ void scan_base_kernel(int* __restrict__ bsum, int nb) {
    __shared__ int sm[256];
    int t = threadIdx.x;
    int carry = 0;
    for (int base = 0; base < nb; base += 256) {
        int i = base + t;
        int v = (i < nb) ? bsum[i] : 0;
        sm[t] = v;
        __syncthreads();
        for (int s = 1; s < 256; s <<= 1) {
            int add = (t >= s) ? sm[t - s] : 0;
            __syncthreads();
            sm[t] += add;
            __syncthreads();
        }
        if (i < nb) bsum[i] = carry + sm[t] - v;  // exclusive
        int tot = sm[255];
        __syncthreads();
        carry += tot;
    }
}

__global__ void scan_final_kernel(const int* __restrict__ cnt, const int* __restrict__ bbase,
                                  int* __restrict__ offv, int n) {
    __shared__ int sm[256];
    int t = threadIdx.x, i = blockIdx.x * 256 + t;
    int v = (i < n) ? cnt[i] : 0;
    sm[t] = v;
    __syncthreads();
    for (int s = 1; s < 256; s <<= 1) {
        int add = (t >= s) ? sm[t - s] : 0;
        __syncthreads();
        sm[t] += add;
        __syncthreads();
    }
    if (i < n) offv[i + 1] = bbase[blockIdx.x] + sm[t];
    if (i == 0) offv[0] = 0;
}

__global__ void fill_kernel(const int* __restrict__ row, const int* __restrict__ col,
                            const int* __restrict__ off, int* __restrict__ fillc,
                            const float* __restrict__ dinv, int2* __restrict__ ep, int E) {
    int e = blockIdx.x * blockDim.x + threadIdx.x;
    if (e < E) {
        int c = col[e], r = row[e];
        int p = atomicAdd(&fillc[c], 1);
        ep[off[c] + p] = make_int2(r, __float_as_int(dinv[r]));
    }
}

// ---------------- conversions ----------------

__global__ void emb_cvt_kernel(const float* __restrict__ emb, const int* __restrict__ xidx,
                               ushort* __restrict__ out, int n) {
    int gid = blockIdx.x * 256 + threadIdx.x;  // one thread per 8 elems
    int total = n * (Dk / 8);
    if (gid >= total) return;
    int node = gid >> 4, seg = gid & 15;
    int src = xidx[node];
    const float* p = &emb[(size_t)src * Dk + seg * 8];
    float4 lo = *(const float4*)p, hi = *(const float4*)(p + 4);
    ushort r[8] = {f2bf(lo.x), f2bf(lo.y), f2bf(lo.z), f2bf(lo.w),
                   f2bf(hi.x), f2bf(hi.y), f2bf(hi.z), f2bf(hi.w)};
    *(short8*)&out[(size_t)gid * 8] = *(short8*)r;
}

// transpose + convert: out[c*K + k] = bf16(in[k*H + c])
__global__ void wcvt_t_kernel(const float* __restrict__ in, ushort* __restrict__ out, int K, int H) {
    int idx = blockIdx.x * 256 + threadIdx.x;
    if (idx >= K * H) return;
    int c = idx / K, k = idx - c * K;
    out[idx] = f2bf(in[(size_t)k * H + c]);
}

// ---------------- 128-tile MFMA GEMM (m97 structure) ----------------
// C[n,Hout] = A[n,KD] @ W[KD,Hout], Wt = W transposed [Hout][KD] bf16.
// BM=128, BK=32, 256 threads (4 waves). BNT = 128 (2x2 waves, 4x4 frags)
// or 64 (4x1 waves, 2x4 frags). Staging via global_load_lds width-16,
// linear LDS [rows][32].

template<int KD, int BNT, bool STATS, bool BIAS>
__global__ __launch_bounds__(256) void gemm128(
    const ushort* __restrict__ A, const ushort* __restrict__ Wt,
    ushort* __restrict__ Cout, int n, int Hout,
    const float* __restrict__ bias, float* __restrict__ stats)
{
    constexpr int WN = (BNT == 128) ? 2 : 1;      // wave cols
    constexpr int MR = (BNT == 128) ? 4 : 2;      // m frags / wave
    constexpr int NR = 4;                          // n frags / wave
    __shared__ ushort lds[(128 + BNT) * 32];
    ushort* As = lds;                // [128][32]
    ushort* Bs = lds + 128 * 32;     // [BNT][32]

    const int tid = threadIdx.x;
    const int lane = tid & 63, wid = tid >> 6;
    const int wr = wid / WN, wc = wid % WN;
    const int lr = lane & 15, lg = lane >> 4;
    const int bm = blockIdx.x * 128;
    const int bn = blockIdx.y * BNT;

    f32x4 acc[MR][NR] = {};

    for (int k0 = 0; k0 < KD; k0 += 32) {
        // stage A: 8KB, 2 calls/thread
        #pragma unroll
        for (int c = 0; c < 2; ++c) {
            int boff = wid * 2048 + c * 1024 + lane * 16;
            int row = boff >> 6;
            int k8 = (boff >> 4) & 3;
            int grow = bm + row; if (grow >= n) grow = n - 1;
            const ushort* src = &A[(size_t)grow * KD + k0 + k8 * 8];
            __builtin_amdgcn_global_load_lds(
                (const __attribute__((address_space(1))) void*)src,
                (__attribute__((address_space(3))) void*)&As[(wid * 2048 + c * 1024) >> 1],
                16, 0, 0);
        }
        // stage B: BNT*64 bytes
        constexpr int BC = BNT * 64 / 4096;   // 2 or 1 calls/thread
        #pragma unroll
        for (int c = 0; c < BC; ++c) {
            int boff = wid * (BNT * 16) + c * 1024 + lane * 16;
            int col = boff >> 6;
            int k8 = (boff >> 4) & 3;
            const ushort* src = &Wt[(size_t)(bn + col) * KD + k0 + k8 * 8];
            __builtin_amdgcn_global_load_lds(
                (const __attribute__((address_space(1))) void*)src,
                (__attribute__((address_space(3))) void*)&Bs[(wid * (BNT * 16) + c * 1024) >> 1],
                16, 0, 0);
        }
        __syncthreads();

        short8 af[MR], bfr[NR];
        #pragma unroll
        for (int m = 0; m < MR; ++m)
            af[m] = *(const short8*)&As[(wr * MR * 16 + m * 16 + lr) * 32 + lg * 8];
        #pragma unroll
        for (int nn = 0; nn < NR; ++nn)
            bfr[nn] = *(const short8*)&Bs[(wc * NR * 16 + nn * 16 + lr) * 32 + lg * 8];
        #pragma unroll
        for (int m = 0; m < MR; ++m)
            #pragma unroll
            for (int nn = 0; nn < NR; ++nn)
                acc[m][nn] = __builtin_amdgcn_mfma_f32_16x16x32_bf16(af[m], bfr[nn], acc[m][nn], 0, 0, 0);
        __syncthreads();
    }

    // epilogue: bias, bf16 store, fused column stats
    float s[NR], q[NR];
    #pragma unroll
    for (int nn = 0; nn < NR; ++nn) { s[nn] = 0.f; q[nn] = 0.f; }
    #pragma unroll
    for (int nn = 0; nn < NR; ++nn) {
        int col = bn + wc * NR * 16 + nn * 16 + lr;
        float bv = BIAS ? bias[col] : 0.f;
        #pragma unroll
        for (int m = 0; m < MR; ++m) {
            #pragma unroll
            for (int i = 0; i < 4; ++i) {
                int row = bm + wr * MR * 16 + m * 16 + lg * 4 + i;
                if (row < n) {
                    float v = acc[m][nn][i] + bv;
                    Cout[(size_t)row * Hout + col] = f2bf(v);
                    if (STATS) { s[nn] += v; q[nn] += v * v; }
                }
            }
        }
    }
    if (STATS) {
        #pragma unroll
        for (int nn = 0; nn < NR; ++nn) {
            s[nn] += __shfl_xor(s[nn], 16);
            q[nn] += __shfl_xor(q[nn], 16);
            s[nn] += __shfl_xor(s[nn], 32);
            q[nn] += __shfl_xor(q[nn], 32);
            if (lg == 0) {
                int col = bn + wc * NR * 16 + nn * 16 + lr;
                atomicAdd(&stats[col], s[nn]);
                atomicAdd(&stats[Hout + col], q[nn]);
            }
        }
    }
}

__global__ void bn_finalize_kernel(const float* __restrict__ stats, const float* __restrict__ g,
                                   const float* __restrict__ be, float* __restrict__ ss,
                                   float invn, int Hf) {
    int f = threadIdx.x;
    float mean = stats[f] * invn;
    float var = stats[Hf + f] * invn - mean * mean;
    float sc = g[f] * rsqrtf(var + BN_EPS);
    ss[f] = sc;
    ss[Hf + f] = fmaf(-mean, sc, be[f]);
}

// y = relu(sc*x + sh), bf16 -> bf16, 8 elems/thread (Hk-wide rows)
__global__ __launch_bounds__(256) void bn_apply_kernel(
    const ushort* __restrict__ in, ushort* __restrict__ out,
    const float* __restrict__ ss, int total8)
{
    int gid = blockIdx.x * 256 + threadIdx.x;
    if (gid >= total8) return;
    size_t idx = (size_t)gid * 8;
    int f = (int)(idx & (Hk - 1));
    short8 a = *(const short8*)&in[idx];
    ushort r[8];
    #pragma unroll
    for (int j = 0; j < 8; ++j) {
        float v = bf2f((ushort)a[j]);
        r[j] = f2bf(fmaxf(fmaf(v, ss[f + j], ss[Hk + f + j]), 0.f));
    }
    *(short8*)&out[idx] = *(short8*)r;
}

// ---------------- CSR-pull aggregation: 1 wave/node, 8 gathers in flight ----------------

template<int FH, bool OUT_F32>
__global__ __launch_bounds__(256) void agg_kernel(
    const ushort* __restrict__ x, const int2* __restrict__ ep, const int* __restrict__ off,
    const float* __restrict__ dinv, const float* __restrict__ bias,
    void* __restrict__ outp, int n)
{
    constexpr int VEC = FH / 64;
    const int lane = threadIdx.x & 63;
    const int node = blockIdx.x * 4 + (threadIdx.x >> 6);
    if (node >= n) return;
    const int fb = lane * VEC;
    const ushort* __restrict__ xb = x + fb;

    float di = dinv[node];
    float acc[VEC];
    {
        ushort t[VEC];
        loadv<VEC>(t, &xb[(size_t)node * FH]);
        #pragma unroll
        for (int v = 0; v < VEC; ++v) acc[v] = di * bf2f(t[v]);
    }
    const int e1 = off[node + 1];
    int e = off[node];
    for (; e + 8 <= e1; e += 8) {
        int2 p[8];
        ushort t[8][VEC];
        #pragma unroll
        for (int j = 0; j < 8; ++j) p[j] = ep[e + j];
        #pragma unroll
        for (int j = 0; j < 8; ++j) loadv<VEC>(t[j], &xb[(size_t)p[j].x * FH]);
        #pragma unroll
        for (int j = 0; j < 8; ++j) {
            float w = __int_as_float(p[j].y);
            #pragma unroll
            for (int v = 0; v < VEC; ++v) acc[v] = fmaf(w, bf2f(t[j][v]), acc[v]);
        }
    }
    for (; e + 2 <= e1; e += 2) {
        int2 p0 = ep[e], p1 = ep[e + 1];
        ushort t0[VEC], t1[VEC];
        loadv<VEC>(t0, &xb[(size_t)p0.x * FH]);
        loadv<VEC>(t1, &xb[(size_t)p1.x * FH]);
        float w0 = __int_as_float(p0.y), w1 = __int_as_float(p1.y);
        #pragma unroll
        for (int v = 0; v < VEC; ++v) {
            acc[v] = fmaf(w0, bf2f(t0[v]), acc[v]);
            acc[v] = fmaf(w1, bf2f(t1[v]), acc[v]);
        }
    }
    if (e < e1) {
        int2 pp = ep[e];
        ushort tt[VEC];
        loadv<VEC>(tt, &xb[(size_t)pp.x * FH]);
        float w = __int_as_float(pp.y);
        #pragma unroll
        for (int v = 0; v < VEC; ++v) acc[v] = fmaf(w, bf2f(tt[v]), acc[v]);
    }
    if (OUT_F32) {
        float* o = (float*)outp + (size_t)node * FH + fb;
        #pragma unroll
        for (int v = 0; v < VEC; ++v) o[v] = fmaf(di, acc[v], bias[fb + v]);
    } else {
        ushort ov[VEC];
        #pragma unroll
        for (int v = 0; v < VEC; ++v) ov[v] = f2bf(di * acc[v]);
        storev<VEC>((ushort*)outp + (size_t)node * FH + fb, ov);
    }
}

// ---------------- host launch ----------------

extern "C" void kernel_launch(void* const* d_in, const int* in_sizes, int n_in,
                              void* d_out, int out_size, void* d_ws, size_t ws_size,
                              hipStream_t stream) {
    const int*   x_idx = (const int*)d_in[0];
    const int*   ei    = (const int*)d_in[1];
    const float* emb   = (const float*)d_in[2];
    const float* W1    = (const float*)d_in[3];
    const float* b1    = (const float*)d_in[4];
    const float* g1    = (const float*)d_in[5];
    const float* be1   = (const float*)d_in[6];
    const float* W2    = (const float*)d_in[7];
    const float* b2    = (const float*)d_in[8];
    const float* g2    = (const float*)d_in[9];
    const float* be2   = (const float*)d_in[10];
    const float* W3    = (const float*)d_in[11];
    const float* b3    = (const float*)d_in[12];

    const int N = in_sizes[0];
    const int E = in_sizes[1] / 2;
    const int* erow = ei;       // source
    const int* ecol = ei + E;   // target

    char* p = (char*)d_ws;
    auto alloc = [&](size_t bytes) { char* q = p; p += (bytes + 255) & ~(size_t)255; return q; };
    const int nb = (N + 255) / 256;
    float*  dinv  = (float*) alloc((size_t)N * 4);
    int*    cnt   = (int*)   alloc((size_t)N * 4);
    int*    off   = (int*)   alloc((size_t)(N + 1) * 4);
    int*    fillc = (int*)   alloc((size_t)N * 4);
    int*    bsum  = (int*)   alloc((size_t)nb * 4);
    int2*   ep    = (int2*)  alloc((size_t)E * 8);
    float*  stats1= (float*) alloc(2 * Hk * 4);
    float*  ss1   = (float*) alloc(2 * Hk * 4);
    float*  stats2= (float*) alloc(2 * Hk * 4);
    float*  ss2   = (float*) alloc(2 * Hk * 4);
    ushort* W1t   = (ushort*)alloc((size_t)Dk * Hk * 2);   // [Hk][Dk]
    ushort* W2t   = (ushort*)alloc((size_t)Hk * Hk * 2);   // [Hk][Hk]
    ushort* W3t   = (ushort*)alloc((size_t)Hk * Ok * 2);   // [Ok][Hk]
    ushort* bufU  = (ushort*)alloc((size_t)N * Hk * 2);
    ushort* embb  = bufU;
    ushort* agg1b = bufU + (size_t)N * Dk;
    ushort* relu1b= bufU;
    ushort* conv1b= (ushort*)alloc((size_t)N * Hk * 2);  // conv1, then conv2
    ushort* agg2b = (ushort*)alloc((size_t)N * Hk * 2);  // agg2, then relu2
    ushort* xl3b  = (ushort*)alloc((size_t)N * Ok * 2);

    // --- graph preprocessing ---
    hipMemsetAsync(cnt, 0, (size_t)N * 4, stream);
    hipMemsetAsync(fillc, 0, (size_t)N * 4, stream);
    hipMemsetAsync(stats1, 0, 2 * Hk * 4, stream);
    hipMemsetAsync(stats2, 0, 2 * Hk * 4, stream);
    count_kernel<<<(E + 255) / 256, 256, 0, stream>>>(ecol, cnt, E);
    dinv_kernel<<<nb, 256, 0, stream>>>(cnt, dinv, N);
    block_sum_kernel<<<nb, 256, 0, stream>>>(cnt, bsum, N);
    scan_base_kernel<<<1, 256, 0, stream>>>(bsum, nb);
    scan_final_kernel<<<nb, 256, 0, stream>>>(cnt, bsum, off, N);
    fill_kernel<<<(E + 255) / 256, 256, 0, stream>>>(erow, ecol, off, fillc, dinv, ep, E);

    // --- input conversions (weights transposed for gload_lds staging) ---
    emb_cvt_kernel<<<(N * (Dk / 8) + 255) / 256, 256, 0, stream>>>(emb, x_idx, embb, N);
    wcvt_t_kernel<<<(Dk * Hk + 255) / 256, 256, 0, stream>>>(W1, W1t, Dk, Hk);
    wcvt_t_kernel<<<(Hk * Hk + 255) / 256, 256, 0, stream>>>(W2, W2t, Hk, Hk);
    wcvt_t_kernel<<<(Hk * Ok + 255) / 256, 256, 0, stream>>>(W3, W3t, Hk, Ok);

    const int rb128 = (N + 127) / 128;
    const int aggBlocks = (N + 3) / 4;
    const int applyBlocks = (N * (Hk / 8) + 255) / 256;

    // --- layer 1 ---
    agg_kernel<Dk, false><<<aggBlocks, 256, 0, stream>>>(embb, ep, off, dinv, nullptr, agg1b, N);
    gemm128<Dk, 128, true, true><<<dim3(rb128, Hk / 128), 256, 0, stream>>>(
        agg1b, W1t, conv1b, N, Hk, b1, stats1);
    bn_finalize_kernel<<<1, Hk, 0, stream>>>(stats1, g1, be1, ss1, 1.0f / N, Hk);
    bn_apply_kernel<<<applyBlocks, 256, 0, stream>>>(conv1b, relu1b, ss1, N * (Hk / 8));

    // --- layer 2 ---
    agg_kernel<Hk, false><<<aggBlocks, 256, 0, stream>>>(relu1b, ep, off, dinv, nullptr, agg2b, N);
    gemm128<Hk, 128, true, true><<<dim3(rb128, Hk / 128), 256, 0, stream>>>(
        agg2b, W2t, conv1b /* conv2 */, N, Hk, b2, stats2);
    bn_finalize_kernel<<<1, Hk, 0, stream>>>(stats2, g2, be2, ss2, 1.0f / N, Hk);
    bn_apply_kernel<<<applyBlocks, 256, 0, stream>>>(conv1b, agg2b /* relu2 */, ss2, N * (Hk / 8));

    // --- layer 3 ---
    gemm128<Hk, 64, false, false><<<dim3(rb128, 1), 256, 0, stream>>>(
        agg2b, W3t, xl3b, N, Ok, nullptr, nullptr);
    agg_kernel<Ok, true><<<aggBlocks, 256, 0, stream>>>(xl3b, ep, off, dinv, b3, d_out, N);
}

// Round 5
// 323.184 us; speedup vs baseline: 2.9179x; 1.1206x over previous
//
#include <hip/hip_runtime.h>
#include <hip/hip_bf16.h>

#define Dk 128
#define Hk 256
#define Ok 64
#define BN_EPS 1e-5f

typedef __attribute__((ext_vector_type(8))) short short8;
typedef __attribute__((ext_vector_type(4))) float f32x4;

static __device__ __forceinline__ float bf2f(ushort u) {
    union { uint32_t i; float f; } c; c.i = ((uint32_t)u) << 16; return c.f;
}
static __device__ __forceinline__ ushort f2bf(float f) {
    union { float f; uint32_t u; } c; c.f = f;
    return (ushort)((c.u + 0x7fffu + ((c.u >> 16) & 1u)) >> 16);
}

template<int V> __device__ __forceinline__ void loadv(ushort* d, const ushort* s);
template<> __device__ __forceinline__ void loadv<1>(ushort* d, const ushort* s) { d[0] = *s; }
template<> __device__ __forceinline__ void loadv<2>(ushort* d, const ushort* s) { *(ushort2*)d = *(const ushort2*)s; }
template<> __device__ __forceinline__ void loadv<4>(ushort* d, const ushort* s) { *(ushort4*)d = *(const ushort4*)s; }
template<int V> __device__ __forceinline__ void storev(ushort* d, const ushort* s);
template<> __device__ __forceinline__ void storev<1>(ushort* d, const ushort* s) { *d = s[0]; }
template<> __device__ __forceinline__ void storev<2>(ushort* d, const ushort* s) { *(ushort2*)d = *(const ushort2*)s; }
template<> __device__ __forceinline__ void storev<4>(ushort* d, const ushort* s) { *(ushort4*)d = *(const ushort4*)s; }

// ---------------- degree / CSR build ----------------

__global__ void count_kernel(const int* __restrict__ col, int* __restrict__ cnt, int E) {
    int e = blockIdx.x * blockDim.x + threadIdx.x;
    if (e < E) atomicAdd(&cnt[col[e]], 1);
}

// dinv + fillc=0 + per-block degree sums, one pass
__global__ void dinv_bsum_kernel(const int* __restrict__ cnt, float* __restrict__ dinv,
                                 int* __restrict__ fillc, int* __restrict__ bsum, int n) {
    __shared__ int sm[256];
    int i = blockIdx.x * 256 + threadIdx.x;
    int c = (i < n) ? cnt[i] : 0;
    if (i < n) { dinv[i] = rsqrtf((float)c + 1.0f); fillc[i] = 0; }
    sm[threadIdx.x] = c;
    __syncthreads();
    for (int s = 128; s; s >>= 1) {
        if (threadIdx.x < s) sm[threadIdx.x] += sm[threadIdx.x + s];
        __syncthreads();
    }
    if (!threadIdx.x) bsum[blockIdx.x] = sm[0];
}

__global__ void scan_base_kernel(int* __restrict__ bsum, int nb) {
    __shared__ int sm[256];
    int t = threadIdx.x;
    int carry = 0;
    for (int base = 0; base < nb; base += 256) {
        int i = base + t;
        int v = (i < nb) ? bsum[i] : 0;
        sm[t] = v;
        __syncthreads();
        for (int s = 1; s < 256; s <<= 1) {
            int add = (t >= s) ? sm[t - s] : 0;
            __syncthreads();
            sm[t] += add;
            __syncthreads();
        }
        if (i < nb) bsum[i] = carry + sm[t] - v;  // exclusive
        int tot = sm[255];
        __syncthreads();
        carry += tot;
    }
}

__global__ void scan_final_kernel(const int* __restrict__ cnt, const int* __restrict__ bbase,
                                  int* __restrict__ offv, int n) {
    __shared__ int sm[256];
    int t = threadIdx.x, i = blockIdx.x * 256 + t;
    int v = (i < n) ? cnt[i] : 0;
    sm[t] = v;
    __syncthreads();
    for (int s = 1; s < 256; s <<= 1) {
        int add = (t >= s) ? sm[t - s] : 0;
        __syncthreads();
        sm[t] += add;
        __syncthreads();
    }
    if (i < n) offv[i + 1] = bbase[blockIdx.x] + sm[t];
    if (i == 0) offv[0] = 0;
}

__global__ void fill_kernel(const int* __restrict__ row, const int* __restrict__ col,
                            const int* __restrict__ off, int* __restrict__ fillc,
                            const float* __restrict__ dinv, int2* __restrict__ ep, int E) {
    int e = blockIdx.x * blockDim.x + threadIdx.x;
    if (e < E) {
        int c = col[e], r = row[e];
        int p = atomicAdd(&fillc[c], 1);
        ep[off[c] + p] = make_int2(r, __float_as_int(dinv[r]));
    }
}

// ---------------- conversions ----------------

__global__ void emb_cvt_kernel(const float* __restrict__ emb, const int* __restrict__ xidx,
                               ushort* __restrict__ out, int n) {
    int gid = blockIdx.x * 256 + threadIdx.x;  // one thread per 8 elems
    int total = n * (Dk / 8);
    if (gid >= total) return;
    int node = gid >> 4, seg = gid & 15;
    int src = xidx[node];
    const float* p = &emb[(size_t)src * Dk + seg * 8];
    float4 lo = *(const float4*)p, hi = *(const float4*)(p + 4);
    ushort r[8] = {f2bf(lo.x), f2bf(lo.y), f2bf(lo.z), f2bf(lo.w),
                   f2bf(hi.x), f2bf(hi.y), f2bf(hi.z), f2bf(hi.w)};
    *(short8*)&out[(size_t)gid * 8] = *(short8*)r;
}

// one kernel: transpose-convert W1,W2,W3 + zero the 1024-float stats block
#define W1SZ (Dk * Hk)
#define W2SZ (Hk * Hk)
#define W3SZ (Hk * Ok)
__global__ void wcvt_all_kernel(const float* __restrict__ W1, const float* __restrict__ W2,
                                const float* __restrict__ W3, ushort* __restrict__ W1t,
                                ushort* __restrict__ W2t, ushort* __restrict__ W3t,
                                float* __restrict__ stats) {
    int gid = blockIdx.x * 256 + threadIdx.x;
    if (blockIdx.x == (W1SZ + W2SZ + W3SZ) / 256) {
        for (int i = threadIdx.x; i < 1024; i += 256) stats[i] = 0.f;
        return;
    }
    if (gid < W1SZ) {
        int c = gid / Dk, k = gid - c * Dk;
        W1t[gid] = f2bf(W1[(size_t)k * Hk + c]);
    } else if (gid < W1SZ + W2SZ) {
        int idx = gid - W1SZ;
        int c = idx / Hk, k = idx - c * Hk;
        W2t[idx] = f2bf(W2[(size_t)k * Hk + c]);
    } else {
        int idx = gid - W1SZ - W2SZ;
        int c = idx / Hk, k = idx - c * Hk;
        W3t[idx] = f2bf(W3[(size_t)k * Ok + c]);
    }
}

// ---------------- 128-tile MFMA GEMM (m97 structure) ----------------
// C[n,Hout] = A[n,KD] @ W[KD,Hout], Wt = [Hout][KD] bf16.
// BN_A: reg-staged A with y = relu(sc*x+sh); sc/sh computed from raw stats
//       (statsIn/g/be/invn) into LDS once per block.

template<int KD, int BNT, bool STATS, bool BIAS, bool BN_A>
__global__ __launch_bounds__(256) void gemm128(
    const ushort* __restrict__ A, const ushort* __restrict__ Wt,
    ushort* __restrict__ Cout, int n, int Hout,
    const float* __restrict__ bias, float* __restrict__ stats,
    const float* __restrict__ statsIn, const float* __restrict__ g,
    const float* __restrict__ be, float invn)
{
    constexpr int WN = (BNT == 128) ? 2 : 1;
    constexpr int MR = (BNT == 128) ? 4 : 2;
    constexpr int NR = 4;
    __shared__ ushort lds[(128 + BNT) * 32];
    __shared__ float ssc[BN_A ? KD : 1];
    __shared__ float ssh[BN_A ? KD : 1];
    ushort* As = lds;
    ushort* Bs = lds + 128 * 32;

    const int tid = threadIdx.x;
    const int lane = tid & 63, wid = tid >> 6;
    const int wr = wid / WN, wc = wid % WN;
    const int lr = lane & 15, lg = lane >> 4;
    const int bm = blockIdx.x * 128;
    const int bn = blockIdx.y * BNT;

    if (BN_A) {
        for (int f = tid; f < KD; f += 256) {
            float mean = statsIn[f] * invn;
            float var = statsIn[KD + f] * invn - mean * mean;
            float sc = g[f] * rsqrtf(var + BN_EPS);
            ssc[f] = sc;
            ssh[f] = fmaf(-mean, sc, be[f]);
        }
        __syncthreads();
    }

    f32x4 acc[MR][NR] = {};

    for (int k0 = 0; k0 < KD; k0 += 32) {
        // stage A
        #pragma unroll
        for (int c = 0; c < 2; ++c) {
            int boff = wid * 2048 + c * 1024 + lane * 16;
            int row = boff >> 6;
            int k8 = (boff >> 4) & 3;
            int grow = bm + row; if (grow >= n) grow = n - 1;
            const ushort* src = &A[(size_t)grow * KD + k0 + k8 * 8];
            if (BN_A) {
                short8 av = *(const short8*)src;
                ushort r[8];
                #pragma unroll
                for (int j = 0; j < 8; ++j) {
                    int kf = k0 + k8 * 8 + j;
                    float v = bf2f((ushort)av[j]);
                    r[j] = f2bf(fmaxf(fmaf(v, ssc[kf], ssh[kf]), 0.f));
                }
                *(short8*)&As[row * 32 + k8 * 8] = *(short8*)r;
            } else {
                __builtin_amdgcn_global_load_lds(
                    (const __attribute__((address_space(1))) void*)src,
                    (__attribute__((address_space(3))) void*)&As[(wid * 2048 + c * 1024) >> 1],
                    16, 0, 0);
            }
        }
        // stage B
        constexpr int BC = BNT * 64 / 4096;
        #pragma unroll
        for (int c = 0; c < BC; ++c) {
            int boff = wid * (BNT * 16) + c * 1024 + lane * 16;
            int col = boff >> 6;
            int k8 = (boff >> 4) & 3;
            const ushort* src = &Wt[(size_t)(bn + col) * KD + k0 + k8 * 8];
            __builtin_amdgcn_global_load_lds(
                (const __attribute__((address_space(1))) void*)src,
                (__attribute__((address_space(3))) void*)&Bs[(wid * (BNT * 16) + c * 1024) >> 1],
                16, 0, 0);
        }
        __syncthreads();

        short8 af[MR], bfr[NR];
        #pragma unroll
        for (int m = 0; m < MR; ++m)
            af[m] = *(const short8*)&As[(wr * MR * 16 + m * 16 + lr) * 32 + lg * 8];
        #pragma unroll
        for (int nn = 0; nn < NR; ++nn)
            bfr[nn] = *(const short8*)&Bs[(wc * NR * 16 + nn * 16 + lr) * 32 + lg * 8];
        #pragma unroll
        for (int m = 0; m < MR; ++m)
            #pragma unroll
            for (int nn = 0; nn < NR; ++nn)
                acc[m][nn] = __builtin_amdgcn_mfma_f32_16x16x32_bf16(af[m], bfr[nn], acc[m][nn], 0, 0, 0);
        __syncthreads();
    }

    float s[NR], q[NR];
    #pragma unroll
    for (int nn = 0; nn < NR; ++nn) { s[nn] = 0.f; q[nn] = 0.f; }
    #pragma unroll
    for (int nn = 0; nn < NR; ++nn) {
        int col = bn + wc * NR * 16 + nn * 16 + lr;
        float bv = BIAS ? bias[col] : 0.f;
        #pragma unroll
        for (int m = 0; m < MR; ++m) {
            #pragma unroll
            for (int i = 0; i < 4; ++i) {
                int row = bm + wr * MR * 16 + m * 16 + lg * 4 + i;
                if (row < n) {
                    float v = acc[m][nn][i] + bv;
                    Cout[(size_t)row * Hout + col] = f2bf(v);
                    if (STATS) { s[nn] += v; q[nn] += v * v; }
                }
            }
        }
    }
    if (STATS) {
        #pragma unroll
        for (int nn = 0; nn < NR; ++nn) {
            s[nn] += __shfl_xor(s[nn], 16);
            q[nn] += __shfl_xor(q[nn], 16);
            s[nn] += __shfl_xor(s[nn], 32);
            q[nn] += __shfl_xor(q[nn], 32);
            if (lg == 0) {
                int col = bn + wc * NR * 16 + nn * 16 + lr;
                atomicAdd(&stats[col], s[nn]);
                atomicAdd(&stats[Hout + col], q[nn]);
            }
        }
    }
}

// ---------------- CSR-pull aggregation: 1 wave/node, 8 gathers in flight ----------------
// MODE 0: plain -> bf16    MODE 1: relu(BN(x)) per gathered elem -> bf16 (BN finalize fused)
// MODE 2: + bias -> f32

template<int FH, int MODE>
__global__ __launch_bounds__(256) void agg_kernel(
    const ushort* __restrict__ x, const int2* __restrict__ ep, const int* __restrict__ off,
    const float* __restrict__ dinv, const float* __restrict__ statsIn,
    const float* __restrict__ g, const float* __restrict__ be, float invn,
    const float* __restrict__ bias, void* __restrict__ outp, int n)
{
    constexpr int VEC = FH / 64;
    const int lane = threadIdx.x & 63;
    const int wid = __builtin_amdgcn_readfirstlane(threadIdx.x >> 6);
    const int node = blockIdx.x * 4 + wid;
    if (node >= n) return;
    const int fb = lane * VEC;
    const ushort* __restrict__ xb = x + fb;

    float sc[VEC], sh[VEC];
    if (MODE == 1) {
        #pragma unroll
        for (int v = 0; v < VEC; ++v) {
            int f = fb + v;
            float mean = statsIn[f] * invn;
            float var = statsIn[FH + f] * invn - mean * mean;
            sc[v] = g[f] * rsqrtf(var + BN_EPS);
            sh[v] = fmaf(-mean, sc[v], be[f]);
        }
    }
    auto xform = [&](ushort u, int v) -> float {
        float val = bf2f(u);
        if (MODE == 1) val = fmaxf(fmaf(val, sc[v], sh[v]), 0.f);
        return val;
    };

    float di = dinv[node];
    float acc[VEC];
    {
        ushort t[VEC];
        loadv<VEC>(t, &xb[(size_t)node * FH]);
        #pragma unroll
        for (int v = 0; v < VEC; ++v) acc[v] = di * xform(t[v], v);
    }
    const int e1 = off[node + 1];
    int e = off[node];
    for (; e + 8 <= e1; e += 8) {
        int2 p[8];
        ushort t[8][VEC];
        #pragma unroll
        for (int j = 0; j < 8; ++j) p[j] = ep[e + j];
        #pragma unroll
        for (int j = 0; j < 8; ++j) loadv<VEC>(t[j], &xb[(size_t)p[j].x * FH]);
        #pragma unroll
        for (int j = 0; j < 8; ++j) {
            float w = __int_as_float(p[j].y);
            #pragma unroll
            for (int v = 0; v < VEC; ++v) acc[v] = fmaf(w, xform(t[j][v], v), acc[v]);
        }
    }
    for (; e + 2 <= e1; e += 2) {
        int2 p0 = ep[e], p1 = ep[e + 1];
        ushort t0[VEC], t1[VEC];
        loadv<VEC>(t0, &xb[(size_t)p0.x * FH]);
        loadv<VEC>(t1, &xb[(size_t)p1.x * FH]);
        float w0 = __int_as_float(p0.y), w1 = __int_as_float(p1.y);
        #pragma unroll
        for (int v = 0; v < VEC; ++v) {
            acc[v] = fmaf(w0, xform(t0[v], v), acc[v]);
            acc[v] = fmaf(w1, xform(t1[v], v), acc[v]);
        }
    }
    if (e < e1) {
        int2 pp = ep[e];
        ushort tt[VEC];
        loadv<VEC>(tt, &xb[(size_t)pp.x * FH]);
        float w = __int_as_float(pp.y);
        #pragma unroll
        for (int v = 0; v < VEC; ++v) acc[v] = fmaf(w, xform(tt[v], v), acc[v]);
    }
    if (MODE == 2) {
        float* o = (float*)outp + (size_t)node * FH + fb;
        #pragma unroll
        for (int v = 0; v < VEC; ++v) o[v] = fmaf(di, acc[v], bias[fb + v]);
    } else {
        ushort ov[VEC];
        #pragma unroll
        for (int v = 0; v < VEC; ++v) ov[v] = f2bf(di * acc[v]);
        storev<VEC>((ushort*)outp + (size_t)node * FH + fb, ov);
    }
}

// ---------------- host launch ----------------

extern "C" void kernel_launch(void* const* d_in, const int* in_sizes, int n_in,
                              void* d_out, int out_size, void* d_ws, size_t ws_size,
                              hipStream_t stream) {
    const int*   x_idx = (const int*)d_in[0];
    const int*   ei    = (const int*)d_in[1];
    const float* emb   = (const float*)d_in[2];
    const float* W1    = (const float*)d_in[3];
    const float* b1    = (const float*)d_in[4];
    const float* g1    = (const float*)d_in[5];
    const float* be1   = (const float*)d_in[6];
    const float* W2    = (const float*)d_in[7];
    const float* b2    = (const float*)d_in[8];
    const float* g2    = (const float*)d_in[9];
    const float* be2   = (const float*)d_in[10];
    const float* W3    = (const float*)d_in[11];
    const float* b3    = (const float*)d_in[12];

    const int N = in_sizes[0];
    const int E = in_sizes[1] / 2;
    const int* erow = ei;       // source
    const int* ecol = ei + E;   // target

    char* p = (char*)d_ws;
    auto alloc = [&](size_t bytes) { char* q = p; p += (bytes + 255) & ~(size_t)255; return q; };
    const int nb = (N + 255) / 256;
    float*  dinv  = (float*) alloc((size_t)N * 4);
    int*    cnt   = (int*)   alloc((size_t)N * 4);
    int*    off   = (int*)   alloc((size_t)(N + 1) * 4);
    int*    fillc = (int*)   alloc((size_t)N * 4);
    int*    bsum  = (int*)   alloc((size_t)nb * 4);
    int2*   ep    = (int2*)  alloc((size_t)E * 8);
    float*  stats = (float*) alloc(1024 * 4);    // stats1[512] | stats2[512]
    float*  stats1 = stats, *stats2 = stats + 512;
    ushort* W1t   = (ushort*)alloc((size_t)Dk * Hk * 2);   // [Hk][Dk]
    ushort* W2t   = (ushort*)alloc((size_t)Hk * Hk * 2);   // [Hk][Hk]
    ushort* W3t   = (ushort*)alloc((size_t)Hk * Ok * 2);   // [Ok][Hk]
    ushort* bufU  = (ushort*)alloc((size_t)N * Hk * 2);    // embb+agg1b, later conv2
    ushort* embb  = bufU;
    ushort* agg1b = bufU + (size_t)N * Dk;
    ushort* conv2b= bufU;
    ushort* conv1b= (ushort*)alloc((size_t)N * Hk * 2);
    ushort* agg2b = (ushort*)alloc((size_t)N * Hk * 2);
    ushort* xl3b  = (ushort*)alloc((size_t)N * Ok * 2);

    const float invn = 1.0f / (float)N;

    // --- graph preprocessing ---
    hipMemsetAsync(cnt, 0, (size_t)N * 4, stream);
    count_kernel<<<(E + 255) / 256, 256, 0, stream>>>(ecol, cnt, E);
    dinv_bsum_kernel<<<nb, 256, 0, stream>>>(cnt, dinv, fillc, bsum, N);
    scan_base_kernel<<<1, 256, 0, stream>>>(bsum, nb);
    scan_final_kernel<<<nb, 256, 0, stream>>>(cnt, bsum, off, N);
    fill_kernel<<<(E + 255) / 256, 256, 0, stream>>>(erow, ecol, off, fillc, dinv, ep, E);

    // --- conversions (+ stats zeroing inside wcvt_all) ---
    emb_cvt_kernel<<<(N * (Dk / 8) + 255) / 256, 256, 0, stream>>>(emb, x_idx, embb, N);
    wcvt_all_kernel<<<(W1SZ + W2SZ + W3SZ) / 256 + 1, 256, 0, stream>>>(
        W1, W2, W3, W1t, W2t, W3t, stats);

    const int rb128 = (N + 127) / 128;
    const int aggBlocks = (N + 3) / 4;

    // --- layer 1: agg(emb) @ W1 + b1 -> conv1 (stats1 fused) ---
    agg_kernel<Dk, 0><<<aggBlocks, 256, 0, stream>>>(
        embb, ep, off, dinv, nullptr, nullptr, nullptr, 0.f, nullptr, agg1b, N);
    gemm128<Dk, 128, true, true, false><<<dim3(rb128, Hk / 128), 256, 0, stream>>>(
        agg1b, W1t, conv1b, N, Hk, b1, stats1, nullptr, nullptr, nullptr, 0.f);

    // --- layer 2: agg(relu(bn(conv1))) @ W2 + b2 -> conv2 (stats2 fused, BN1 fused in agg) ---
    agg_kernel<Hk, 1><<<aggBlocks, 256, 0, stream>>>(
        conv1b, ep, off, dinv, stats1, g1, be1, invn, nullptr, agg2b, N);
    gemm128<Hk, 128, true, true, false><<<dim3(rb128, Hk / 128), 256, 0, stream>>>(
        agg2b, W2t, conv2b, N, Hk, b2, stats2, nullptr, nullptr, nullptr, 0.f);

    // --- layer 3: (relu(bn(conv2)) @ W3) aggregated + b3 -> d_out (BN2 fused in GEMM A-staging) ---
    gemm128<Hk, 64, false, false, true><<<dim3(rb128, 1), 256, 0, stream>>>(
        conv2b, W3t, xl3b, N, Ok, nullptr, nullptr, stats2, g2, be2, invn);
    agg_kernel<Ok, 2><<<aggBlocks, 256, 0, stream>>>(
        xl3b, ep, off, dinv, nullptr, nullptr, nullptr, 0.f, b3, d_out, N);
}

// Round 6
// 284.439 us; speedup vs baseline: 3.3154x; 1.1362x over previous
//
#include <hip/hip_runtime.h>
#include <hip/hip_bf16.h>

#define Dk 128
#define Hk 256
#define Ok 64
#define BN_EPS 1e-5f

typedef __attribute__((ext_vector_type(8))) short short8;
typedef __attribute__((ext_vector_type(4))) float f32x4;

static __device__ __forceinline__ float bf2f(ushort u) {
    union { uint32_t i; float f; } c; c.i = ((uint32_t)u) << 16; return c.f;
}
static __device__ __forceinline__ ushort f2bf(float f) {
    union { float f; uint32_t u; } c; c.f = f;
    return (ushort)((c.u + 0x7fffu + ((c.u >> 16) & 1u)) >> 16);
}

template<int V> __device__ __forceinline__ void loadv(ushort* d, const ushort* s);
template<> __device__ __forceinline__ void loadv<1>(ushort* d, const ushort* s) { d[0] = *s; }
template<> __device__ __forceinline__ void loadv<2>(ushort* d, const ushort* s) { *(ushort2*)d = *(const ushort2*)s; }
template<> __device__ __forceinline__ void loadv<4>(ushort* d, const ushort* s) { *(ushort4*)d = *(const ushort4*)s; }
template<int V> __device__ __forceinline__ void storev(ushort* d, const ushort* s);
template<> __device__ __forceinline__ void storev<1>(ushort* d, const ushort* s) { *d = s[0]; }
template<> __device__ __forceinline__ void storev<2>(ushort* d, const ushort* s) { *(ushort2*)d = *(const ushort2*)s; }
template<> __device__ __forceinline__ void storev<4>(ushort* d, const ushort* s) { *(ushort4*)d = *(const ushort4*)s; }

// ---------------- degree / CSR build ----------------

__global__ void count_kernel(const int* __restrict__ col, int* __restrict__ cnt, int E) {
    int e = blockIdx.x * blockDim.x + threadIdx.x;
    if (e < E) atomicAdd(&cnt[col[e]], 1);
}

__global__ void dinv_bsum_kernel(const int* __restrict__ cnt, float* __restrict__ dinv,
                                 int* __restrict__ fillc, int* __restrict__ bsum, int n) {
    __shared__ int sm[256];
    int i = blockIdx.x * 256 + threadIdx.x;
    int c = (i < n) ? cnt[i] : 0;
    if (i < n) { dinv[i] = rsqrtf((float)c + 1.0f); fillc[i] = 0; }
    sm[threadIdx.x] = c;
    __syncthreads();
    for (int s = 128; s; s >>= 1) {
        if (threadIdx.x < s) sm[threadIdx.x] += sm[threadIdx.x + s];
        __syncthreads();
    }
    if (!threadIdx.x) bsum[blockIdx.x] = sm[0];
}

__global__ void scan_base_kernel(int* __restrict__ bsum, int nb) {
    __shared__ int sm[256];
    int t = threadIdx.x;
    int carry = 0;
    for (int base = 0; base < nb; base += 256) {
        int i = base + t;
        int v = (i < nb) ? bsum[i] : 0;
        sm[t] = v;
        __syncthreads();
        for (int s = 1; s < 256; s <<= 1) {
            int add = (t >= s) ? sm[t - s] : 0;
            __syncthreads();
            sm[t] += add;
            __syncthreads();
        }
        if (i < nb) bsum[i] = carry + sm[t] - v;  // exclusive
        int tot = sm[255];
        __syncthreads();
        carry += tot;
    }
}

__global__ void scan_final_kernel(const int* __restrict__ cnt, const int* __restrict__ bbase,
                                  int* __restrict__ offv, int n) {
    __shared__ int sm[256];
    int t = threadIdx.x, i = blockIdx.x * 256 + t;
    int v = (i < n) ? cnt[i] : 0;
    sm[t] = v;
    __syncthreads();
    for (int s = 1; s < 256; s <<= 1) {
        int add = (t >= s) ? sm[t - s] : 0;
        __syncthreads();
        sm[t] += add;
        __syncthreads();
    }
    if (i < n) offv[i + 1] = bbase[blockIdx.x] + sm[t];
    if (i == 0) offv[0] = 0;
}

__global__ void fill_kernel(const int* __restrict__ row, const int* __restrict__ col,
                            const int* __restrict__ off, int* __restrict__ fillc,
                            const float* __restrict__ dinv, int2* __restrict__ ep, int E) {
    int e = blockIdx.x * blockDim.x + threadIdx.x;
    if (e < E) {
        int c = col[e], r = row[e];
        int p = atomicAdd(&fillc[c], 1);
        ep[off[c] + p] = make_int2(r, __float_as_int(dinv[r]));
    }
}

// ---------------- conversions ----------------

__global__ void emb_cvt_kernel(const float* __restrict__ emb, const int* __restrict__ xidx,
                               ushort* __restrict__ out, int n) {
    int gid = blockIdx.x * 256 + threadIdx.x;
    int total = n * (Dk / 8);
    if (gid >= total) return;
    int node = gid >> 4, seg = gid & 15;
    int src = xidx[node];
    const float* p = &emb[(size_t)src * Dk + seg * 8];
    float4 lo = *(const float4*)p, hi = *(const float4*)(p + 4);
    ushort r[8] = {f2bf(lo.x), f2bf(lo.y), f2bf(lo.z), f2bf(lo.w),
                   f2bf(hi.x), f2bf(hi.y), f2bf(hi.z), f2bf(hi.w)};
    *(short8*)&out[(size_t)gid * 8] = *(short8*)r;
}

// transpose-convert W1,W2,W3 + zero the 2x64x512 stats-partials block
#define W1SZ (Dk * Hk)
#define W2SZ (Hk * Hk)
#define W3SZ (Hk * Ok)
#define WBLK ((W1SZ + W2SZ + W3SZ) / 256)
#define STATSP_FLOATS (2 * 64 * 512)
__global__ void wcvt_all_kernel(const float* __restrict__ W1, const float* __restrict__ W2,
                                const float* __restrict__ W3, ushort* __restrict__ W1t,
                                ushort* __restrict__ W2t, ushort* __restrict__ W3t,
                                float* __restrict__ statsP) {
    int bid = blockIdx.x;
    if (bid >= WBLK) {
        int idx = (bid - WBLK) * 1024 + threadIdx.x * 4;
        if (idx < STATSP_FLOATS)
            *(float4*)&statsP[idx] = make_float4(0.f, 0.f, 0.f, 0.f);
        return;
    }
    int gid = bid * 256 + threadIdx.x;
    if (gid < W1SZ) {
        int c = gid / Dk, k = gid - c * Dk;
        W1t[gid] = f2bf(W1[(size_t)k * Hk + c]);
    } else if (gid < W1SZ + W2SZ) {
        int idx = gid - W1SZ;
        int c = idx / Hk, k = idx - c * Hk;
        W2t[idx] = f2bf(W2[(size_t)k * Hk + c]);
    } else {
        int idx = gid - W1SZ - W2SZ;
        int c = idx / Hk, k = idx - c * Hk;
        W3t[idx] = f2bf(W3[(size_t)k * Ok + c]);
    }
}

// reduce 64-slice partials -> sc/sh
__global__ void bn_finalize_kernel(const float* __restrict__ statsP, const float* __restrict__ g,
                                   const float* __restrict__ be, float* __restrict__ ss,
                                   float invn) {
    int f = threadIdx.x;  // 256
    float sum = 0.f, sq = 0.f;
    for (int s = 0; s < 64; ++s) {
        sum += statsP[s * 512 + f];
        sq  += statsP[s * 512 + 256 + f];
    }
    float mean = sum * invn;
    float var = sq * invn - mean * mean;
    float sc = g[f] * rsqrtf(var + BN_EPS);
    ss[f] = sc;
    ss[256 + f] = fmaf(-mean, sc, be[f]);
}

// ---------------- 128-tile MFMA GEMM, double-buffered 2-phase ----------------
// C[n,Hout] = A[n,KD] @ W[KD,Hout], Wt = [Hout][KD] bf16.
// STATS: per-column sum/sq atomics into 64-way partial slices statsP[bx&63][512].
// BN_A: reg-staged A with y = relu(sc*x+sh) from precomputed ss (LDS-cached).

template<int KD, int BNT, bool STATS, bool BIAS, bool BN_A>
__global__ __launch_bounds__(256) void gemm128(
    const ushort* __restrict__ A, const ushort* __restrict__ Wt,
    ushort* __restrict__ Cout, int n, int Hout,
    const float* __restrict__ bias, float* __restrict__ statsP,
    const float* __restrict__ ss)
{
    constexpr int WN = (BNT == 128) ? 2 : 1;
    constexpr int MR = (BNT == 128) ? 4 : 2;
    constexpr int NR = 4;
    constexpr int TILE = (128 + BNT) * 32;      // ushorts per K-step buffer
    constexpr int NT = KD / 32;
    __shared__ ushort lds[2 * TILE];
    __shared__ float ssc[BN_A ? KD : 1];
    __shared__ float ssh[BN_A ? KD : 1];

    const int tid = threadIdx.x;
    const int lane = tid & 63, wid = tid >> 6;
    const int wr = wid / WN, wc = wid % WN;
    const int lr = lane & 15, lg = lane >> 4;
    const int bm = blockIdx.x * 128;
    const int bn = blockIdx.y * BNT;

    if (BN_A) {
        for (int f = tid; f < KD; f += 256) {
            ssc[f] = ss[f];
            ssh[f] = ss[KD + f];
        }
        __syncthreads();
    }

    auto stage = [&](int buf, int k0) {
        ushort* As = lds + buf * TILE;
        ushort* Bs = As + 128 * 32;
        #pragma unroll
        for (int c = 0; c < 2; ++c) {
            int boff = wid * 2048 + c * 1024 + lane * 16;
            int row = boff >> 6;
            int k8 = (boff >> 4) & 3;
            int grow = bm + row; if (grow >= n) grow = n - 1;
            const ushort* src = &A[(size_t)grow * KD + k0 + k8 * 8];
            if (BN_A) {
                short8 av = *(const short8*)src;
                ushort r[8];
                #pragma unroll
                for (int j = 0; j < 8; ++j) {
                    int kf = k0 + k8 * 8 + j;
                    float v = bf2f((ushort)av[j]);
                    r[j] = f2bf(fmaxf(fmaf(v, ssc[kf], ssh[kf]), 0.f));
                }
                *(short8*)&As[row * 32 + k8 * 8] = *(short8*)r;
            } else {
                __builtin_amdgcn_global_load_lds(
                    (const __attribute__((address_space(1))) void*)src,
                    (__attribute__((address_space(3))) void*)&As[(wid * 2048 + c * 1024) >> 1],
                    16, 0, 0);
            }
        }
        constexpr int BC = BNT * 64 / 4096;
        #pragma unroll
        for (int c = 0; c < BC; ++c) {
            int boff = wid * (BNT * 16) + c * 1024 + lane * 16;
            int col = boff >> 6;
            int k8 = (boff >> 4) & 3;
            const ushort* src = &Wt[(size_t)(bn + col) * KD + k0 + k8 * 8];
            __builtin_amdgcn_global_load_lds(
                (const __attribute__((address_space(1))) void*)src,
                (__attribute__((address_space(3))) void*)&Bs[(wid * (BNT * 16) + c * 1024) >> 1],
                16, 0, 0);
        }
    };

    f32x4 acc[MR][NR] = {};

    stage(0, 0);
    __syncthreads();
    int cur = 0;
    for (int t = 0; t < NT; ++t) {
        if (t + 1 < NT) stage(cur ^ 1, (t + 1) * 32);   // prefetch flies under compute
        ushort* As = lds + cur * TILE;
        ushort* Bs = As + 128 * 32;
        short8 af[MR], bfr[NR];
        #pragma unroll
        for (int m = 0; m < MR; ++m)
            af[m] = *(const short8*)&As[(wr * MR * 16 + m * 16 + lr) * 32 + lg * 8];
        #pragma unroll
        for (int nn = 0; nn < NR; ++nn)
            bfr[nn] = *(const short8*)&Bs[(wc * NR * 16 + nn * 16 + lr) * 32 + lg * 8];
        #pragma unroll
        for (int m = 0; m < MR; ++m)
            #pragma unroll
            for (int nn = 0; nn < NR; ++nn)
                acc[m][nn] = __builtin_amdgcn_mfma_f32_16x16x32_bf16(af[m], bfr[nn], acc[m][nn], 0, 0, 0);
        __syncthreads();   // drains prefetch loads (vmcnt0+lgkm0) + barrier
        cur ^= 1;
    }

    float s[NR], q[NR];
    #pragma unroll
    for (int nn = 0; nn < NR; ++nn) { s[nn] = 0.f; q[nn] = 0.f; }
    #pragma unroll
    for (int nn = 0; nn < NR; ++nn) {
        int col = bn + wc * NR * 16 + nn * 16 + lr;
        float bv = BIAS ? bias[col] : 0.f;
        #pragma unroll
        for (int m = 0; m < MR; ++m) {
            #pragma unroll
            for (int i = 0; i < 4; ++i) {
                int row = bm + wr * MR * 16 + m * 16 + lg * 4 + i;
                if (row < n) {
                    float v = acc[m][nn][i] + bv;
                    Cout[(size_t)row * Hout + col] = f2bf(v);
                    if (STATS) { s[nn] += v; q[nn] += v * v; }
                }
            }
        }
    }
    if (STATS) {
        float* sp = statsP + (size_t)(blockIdx.x & 63) * 512;
        #pragma unroll
        for (int nn = 0; nn < NR; ++nn) {
            s[nn] += __shfl_xor(s[nn], 16);
            q[nn] += __shfl_xor(q[nn], 16);
            s[nn] += __shfl_xor(s[nn], 32);
            q[nn] += __shfl_xor(q[nn], 32);
            if (lg == 0) {
                int col = bn + wc * NR * 16 + nn * 16 + lr;
                atomicAdd(&sp[col], s[nn]);
                atomicAdd(&sp[256 + col], q[nn]);
            }
        }
    }
}

// ---------------- CSR-pull aggregation: 1 wave/node, 8 gathers in flight ----------------
// MODE 0: plain -> bf16    MODE 1: relu(sc*x+sh) per gathered elem -> bf16
// MODE 2: + bias -> f32

template<int FH, int MODE>
__global__ __launch_bounds__(256) void agg_kernel(
    const ushort* __restrict__ x, const int2* __restrict__ ep, const int* __restrict__ off,
    const float* __restrict__ dinv, const float* __restrict__ ss,
    const float* __restrict__ bias, void* __restrict__ outp, int n)
{
    constexpr int VEC = FH / 64;
    const int lane = threadIdx.x & 63;
    const int wid = __builtin_amdgcn_readfirstlane(threadIdx.x >> 6);
    const int node = blockIdx.x * 4 + wid;
    if (node >= n) return;
    const int fb = lane * VEC;
    const ushort* __restrict__ xb = x + fb;

    float sc[VEC], sh[VEC];
    if (MODE == 1) {
        #pragma unroll
        for (int v = 0; v < VEC; ++v) { sc[v] = ss[fb + v]; sh[v] = ss[FH + fb + v]; }
    }
    auto xform = [&](ushort u, int v) -> float {
        float val = bf2f(u);
        if (MODE == 1) val = fmaxf(fmaf(val, sc[v], sh[v]), 0.f);
        return val;
    };

    float di = dinv[node];
    float acc[VEC];
    {
        ushort t[VEC];
        loadv<VEC>(t, &xb[(size_t)node * FH]);
        #pragma unroll
        for (int v = 0; v < VEC; ++v) acc[v] = di * xform(t[v], v);
    }
    const int e1 = off[node + 1];
    int e = off[node];
    for (; e + 8 <= e1; e += 8) {
        int2 p[8];
        ushort t[8][VEC];
        #pragma unroll
        for (int j = 0; j < 8; ++j) p[j] = ep[e + j];
        #pragma unroll
        for (int j = 0; j < 8; ++j) loadv<VEC>(t[j], &xb[(size_t)p[j].x * FH]);
        #pragma unroll
        for (int j = 0; j < 8; ++j) {
            float w = __int_as_float(p[j].y);
            #pragma unroll
            for (int v = 0; v < VEC; ++v) acc[v] = fmaf(w, xform(t[j][v], v), acc[v]);
        }
    }
    for (; e + 2 <= e1; e += 2) {
        int2 p0 = ep[e], p1 = ep[e + 1];
        ushort t0[VEC], t1[VEC];
        loadv<VEC>(t0, &xb[(size_t)p0.x * FH]);
        loadv<VEC>(t1, &xb[(size_t)p1.x * FH]);
        float w0 = __int_as_float(p0.y), w1 = __int_as_float(p1.y);
        #pragma unroll
        for (int v = 0; v < VEC; ++v) {
            acc[v] = fmaf(w0, xform(t0[v], v), acc[v]);
            acc[v] = fmaf(w1, xform(t1[v], v), acc[v]);
        }
    }
    if (e < e1) {
        int2 pp = ep[e];
        ushort tt[VEC];
        loadv<VEC>(tt, &xb[(size_t)pp.x * FH]);
        float w = __int_as_float(pp.y);
        #pragma unroll
        for (int v = 0; v < VEC; ++v) acc[v] = fmaf(w, xform(tt[v], v), acc[v]);
    }
    if (MODE == 2) {
        float* o = (float*)outp + (size_t)node * FH + fb;
        #pragma unroll
        for (int v = 0; v < VEC; ++v) o[v] = fmaf(di, acc[v], bias[fb + v]);
    } else {
        ushort ov[VEC];
        #pragma unroll
        for (int v = 0; v < VEC; ++v) ov[v] = f2bf(di * acc[v]);
        storev<VEC>((ushort*)outp + (size_t)node * FH + fb, ov);
    }
}

// ---------------- host launch ----------------

extern "C" void kernel_launch(void* const* d_in, const int* in_sizes, int n_in,
                              void* d_out, int out_size, void* d_ws, size_t ws_size,
                              hipStream_t stream) {
    const int*   x_idx = (const int*)d_in[0];
    const int*   ei    = (const int*)d_in[1];
    const float* emb   = (const float*)d_in[2];
    const float* W1    = (const float*)d_in[3];
    const float* b1    = (const float*)d_in[4];
    const float* g1    = (const float*)d_in[5];
    const float* be1   = (const float*)d_in[6];
    const float* W2    = (const float*)d_in[7];
    const float* b2    = (const float*)d_in[8];
    const float* g2    = (const float*)d_in[9];
    const float* be2   = (const float*)d_in[10];
    const float* W3    = (const float*)d_in[11];
    const float* b3    = (const float*)d_in[12];

    const int N = in_sizes[0];
    const int E = in_sizes[1] / 2;
    const int* erow = ei;       // source
    const int* ecol = ei + E;   // target

    char* p = (char*)d_ws;
    auto alloc = [&](size_t bytes) { char* q = p; p += (bytes + 255) & ~(size_t)255; return q; };
    const int nb = (N + 255) / 256;
    float*  dinv  = (float*) alloc((size_t)N * 4);
    int*    cnt   = (int*)   alloc((size_t)N * 4);
    int*    off   = (int*)   alloc((size_t)(N + 1) * 4);
    int*    fillc = (int*)   alloc((size_t)N * 4);
    int*    bsum  = (int*)   alloc((size_t)nb * 4);
    int2*   ep    = (int2*)  alloc((size_t)E * 8);
    float*  statsP= (float*) alloc((size_t)STATSP_FLOATS * 4);  // 2 layers x 64 x 512
    float*  stats1P = statsP, *stats2P = statsP + 64 * 512;
    float*  ss1   = (float*) alloc(512 * 4);
    float*  ss2   = (float*) alloc(512 * 4);
    ushort* W1t   = (ushort*)alloc((size_t)Dk * Hk * 2);   // [Hk][Dk]
    ushort* W2t   = (ushort*)alloc((size_t)Hk * Hk * 2);   // [Hk][Hk]
    ushort* W3t   = (ushort*)alloc((size_t)Hk * Ok * 2);   // [Ok][Hk]
    ushort* bufU  = (ushort*)alloc((size_t)N * Hk * 2);    // embb+agg1b, later conv2
    ushort* embb  = bufU;
    ushort* agg1b = bufU + (size_t)N * Dk;
    ushort* conv2b= bufU;
    ushort* conv1b= (ushort*)alloc((size_t)N * Hk * 2);
    ushort* agg2b = (ushort*)alloc((size_t)N * Hk * 2);
    ushort* xl3b  = (ushort*)alloc((size_t)N * Ok * 2);

    const float invn = 1.0f / (float)N;

    // --- graph preprocessing ---
    hipMemsetAsync(cnt, 0, (size_t)N * 4, stream);
    count_kernel<<<(E + 255) / 256, 256, 0, stream>>>(ecol, cnt, E);
    dinv_bsum_kernel<<<nb, 256, 0, stream>>>(cnt, dinv, fillc, bsum, N);
    scan_base_kernel<<<1, 256, 0, stream>>>(bsum, nb);
    scan_final_kernel<<<nb, 256, 0, stream>>>(cnt, bsum, off, N);
    fill_kernel<<<(E + 255) / 256, 256, 0, stream>>>(erow, ecol, off, fillc, dinv, ep, E);

    // --- conversions (+ statsP zeroing) ---
    emb_cvt_kernel<<<(N * (Dk / 8) + 255) / 256, 256, 0, stream>>>(emb, x_idx, embb, N);
    wcvt_all_kernel<<<WBLK + (STATSP_FLOATS + 1023) / 1024, 256, 0, stream>>>(
        W1, W2, W3, W1t, W2t, W3t, statsP);

    const int rb128 = (N + 127) / 128;
    const int aggBlocks = (N + 3) / 4;

    // --- layer 1: agg(emb) @ W1 + b1 -> conv1 (stats1 fused, 64-way partials) ---
    agg_kernel<Dk, 0><<<aggBlocks, 256, 0, stream>>>(
        embb, ep, off, dinv, nullptr, nullptr, agg1b, N);
    gemm128<Dk, 128, true, true, false><<<dim3(rb128, Hk / 128), 256, 0, stream>>>(
        agg1b, W1t, conv1b, N, Hk, b1, stats1P, nullptr);
    bn_finalize_kernel<<<1, 256, 0, stream>>>(stats1P, g1, be1, ss1, invn);

    // --- layer 2: agg(relu(bn(conv1))) @ W2 + b2 -> conv2 ---
    agg_kernel<Hk, 1><<<aggBlocks, 256, 0, stream>>>(
        conv1b, ep, off, dinv, ss1, nullptr, agg2b, N);
    gemm128<Hk, 128, true, true, false><<<dim3(rb128, Hk / 128), 256, 0, stream>>>(
        agg2b, W2t, conv2b, N, Hk, b2, stats2P, nullptr);
    bn_finalize_kernel<<<1, 256, 0, stream>>>(stats2P, g2, be2, ss2, invn);

    // --- layer 3: (relu(bn(conv2)) @ W3) aggregated + b3 -> d_out ---
    gemm128<Hk, 64, false, false, true><<<dim3(rb128, 1), 256, 0, stream>>>(
        conv2b, W3t, xl3b, N, Ok, nullptr, nullptr, ss2);
    agg_kernel<Ok, 2><<<aggBlocks, 256, 0, stream>>>(
        xl3b, ep, off, dinv, nullptr, b3, d_out, N);
}